// Round 13
// baseline (267.579 us; speedup 1.0000x reference)
//
#include <hip/hip_runtime.h>
#include <hip/hip_bf16.h>

typedef __attribute__((ext_vector_type(8))) short short8;
typedef __attribute__((ext_vector_type(4))) float f32x4;
typedef __attribute__((ext_vector_type(4))) unsigned int u32x4;
using u16 = unsigned short;
typedef unsigned int u32;

__device__ __forceinline__ u16 f2bf(float f) {
    u32 u = __builtin_bit_cast(u32, f);
    u32 r = u + 0x7FFFu + ((u >> 16) & 1u);
    return (u16)(r >> 16);
}

__device__ __forceinline__ float bf2f(u32 w) {  // low 16 bits = bf16
    return __builtin_bit_cast(float, w << 16);
}
__device__ __forceinline__ float bf2f_hi(u32 w) {
    return __builtin_bit_cast(float, w & 0xFFFF0000u);
}

__device__ __forceinline__ float exp2fast(float x) {
    return __builtin_amdgcn_exp2f(x);  // v_exp_f32
}

__device__ __forceinline__ u32 cvtpk(float lo, float hi) {
    u32 r;
    asm("v_cvt_pk_bf16_f32 %0, %1, %2" : "=v"(r) : "v"(lo), "v"(hi));
    return r;
}

__device__ __forceinline__ void async_load16(const void* g, void* l) {
    __builtin_amdgcn_global_load_lds(
        (const __attribute__((address_space(1))) void*)g,
        (__attribute__((address_space(3))) void*)l, 16, 0, 0);
}

__device__ __forceinline__ void wg_barrier() {
    asm volatile("" ::: "memory");
    __builtin_amdgcn_s_barrier();
    asm volatile("" ::: "memory");
}

// ---------------- vectorized transpose + f32->bf16: w[K][N] -> wt[N][K], 64x64 tiles ----------------
// float4 reads, stride-65 LDS (<=2-way banks both phases), uint2 bf16 writes.
__device__ __forceinline__ void convt64_body(const float* __restrict__ w,
                                             u16* __restrict__ wt, int K, int N,
                                             int bn, int bk) {
    __shared__ float tile[64][65];
    int tid = threadIdx.x;
    int rr = tid >> 4;         // 0..15
    int cc = (tid & 15) * 4;   // 0..60
#pragma unroll
    for (int p = 0; p < 4; p++) {
        int r = p * 16 + rr;
        float4 v = *(const float4*)(w + (size_t)(bk + r) * N + bn + cc);
        tile[r][cc] = v.x; tile[r][cc + 1] = v.y; tile[r][cc + 2] = v.z; tile[r][cc + 3] = v.w;
    }
    __syncthreads();
#pragma unroll
    for (int p = 0; p < 4; p++) {
        int n = p * 16 + rr;
        float v0 = tile[cc + 0][n], v1 = tile[cc + 1][n];
        float v2 = tile[cc + 2][n], v3 = tile[cc + 3][n];
        uint2 o;
        o.x = (u32)f2bf(v0) | ((u32)f2bf(v1) << 16);
        o.y = (u32)f2bf(v2) | ((u32)f2bf(v3) << 16);
        *(uint2*)(wt + (size_t)(bn + n) * K + bk + cc) = o;
    }
}

__global__ __launch_bounds__(256) void convt64_kernel(const float* __restrict__ w,
                                                      u16* __restrict__ wt, int K, int N) {
    convt64_body(w, wt, K, N, blockIdx.x * 64, blockIdx.y * 64);
}

// 4 square 1024x1024 transposes in one launch
__global__ __launch_bounds__(256) void convt64x4_kernel(const float* __restrict__ wa,
                                                        const float* __restrict__ wb,
                                                        const float* __restrict__ wc,
                                                        const float* __restrict__ wd,
                                                        u16* __restrict__ da,
                                                        u16* __restrict__ db,
                                                        u16* __restrict__ dc,
                                                        u16* __restrict__ dd) {
    int z = blockIdx.z;
    const float* w = (z == 0) ? wa : (z == 1) ? wb : (z == 2) ? wc : wd;
    u16* wt = (z == 0) ? da : (z == 1) ? db : (z == 2) ? dc : dd;
    convt64_body(w, wt, 1024, 1024, blockIdx.x * 64, blockIdx.y * 64);
}

// ---------------- V transpose (bf16, u32-vectorized): qkv V-part -> vT[b*1024+col][2048] ----------------
// 64 s x 64 col tiles; stride-74 u16 LDS.
__global__ __launch_bounds__(256) void vtrans64_kernel(const u16* __restrict__ qkv,
                                                       u16* __restrict__ vT) {
    __shared__ u16 tile[64][74];
    int bs = blockIdx.x * 64;   // s tile
    int bc = blockIdx.y * 64;   // col tile
    int b  = blockIdx.z;
    int tid = threadIdx.x;
    int l5 = tid & 31, h3 = tid >> 5;  // 32 x 8
#pragma unroll
    for (int p = 0; p < 8; p++) {
        int sr = p * 8 + h3;
        u32 v = *(const u32*)(qkv + (size_t)(b * 2048 + bs + sr) * 3072 + 2048 + bc + l5 * 2);
        *(u32*)&tile[sr][l5 * 2] = v;
    }
    __syncthreads();
#pragma unroll
    for (int p = 0; p < 8; p++) {
        int n = p * 8 + h3;
        int s2 = l5 * 2;
        u32 a = tile[s2][n];
        u32 bb = tile[s2 + 1][n];
        *(u32*)(vT + (size_t)(b * 1024 + bc + n) * 2048 + bs + s2) = a | (bb << 16);
    }
}

// ---------------- LayerNorm (fp32 in, bf16 out) ----------------
__global__ __launch_bounds__(256) void ln_kernel(const float* __restrict__ x,
                                                 const float* __restrict__ ga,
                                                 const float* __restrict__ gb,
                                                 u16* __restrict__ out) {
    int row = blockIdx.x;
    const float4* xr = (const float4*)(x + (size_t)row * 1024);
    float4 v = xr[threadIdx.x];
    float s  = v.x + v.y + v.z + v.w;
    float s2 = v.x * v.x + v.y * v.y + v.z * v.z + v.w * v.w;
#pragma unroll
    for (int off = 32; off; off >>= 1) {
        s  += __shfl_down(s, off);
        s2 += __shfl_down(s2, off);
    }
    __shared__ float rs[4], rs2[4];
    int wid = threadIdx.x >> 6, lane = threadIdx.x & 63;
    if (lane == 0) { rs[wid] = s; rs2[wid] = s2; }
    __syncthreads();
    float S  = rs[0] + rs[1] + rs[2] + rs[3];
    float S2 = rs2[0] + rs2[1] + rs2[2] + rs2[3];
    float mean = S * (1.0f / 1024.0f);
    float var  = fmaxf((S2 - 1024.0f * mean * mean) * (1.0f / 1023.0f), 0.0f);
    float scale = ga[0] / (sqrtf(var) + 1e-6f);
    float shift = gb[0] - mean * scale;
    uint2 pv;
    pv.x = (u32)f2bf(v.x * scale + shift) | ((u32)f2bf(v.y * scale + shift) << 16);
    pv.y = (u32)f2bf(v.z * scale + shift) | ((u32)f2bf(v.w * scale + shift) << 16);
    *(uint2*)(out + (size_t)row * 1024 + threadIdx.x * 4) = pv;
}

// ---- fused reduce (3 bf16 partials): dst = dst + p0 + p1 + p2 + bias + resid ----
__global__ __launch_bounds__(256) void addbias3b_kernel(float* __restrict__ dst,
                                                        const u16* __restrict__ p0,
                                                        const u16* __restrict__ p1,
                                                        const u16* __restrict__ p2,
                                                        const float* __restrict__ bias,
                                                        const float* __restrict__ resid) {
    int i4 = blockIdx.x * 256 + threadIdx.x;
    float4 d  = ((const float4*)dst)[i4];
    uint2 ua = ((const uint2*)p0)[i4];
    uint2 ub = ((const uint2*)p1)[i4];
    uint2 uc = ((const uint2*)p2)[i4];
    float4 rr = ((const float4*)resid)[i4];
    float4 bb = *(const float4*)(bias + ((i4 * 4) & 1023));
    d.x += bf2f(ua.x) + bf2f(ub.x) + bf2f(uc.x) + bb.x + rr.x;
    d.y += bf2f_hi(ua.x) + bf2f_hi(ub.x) + bf2f_hi(uc.x) + bb.y + rr.y;
    d.z += bf2f(ua.y) + bf2f(ub.y) + bf2f(uc.y) + bb.z + rr.z;
    d.w += bf2f_hi(ua.y) + bf2f_hi(ub.y) + bf2f_hi(uc.y) + bb.w + rr.w;
    ((float4*)dst)[i4] = d;
}

// ---- fused reduce (3 bf16 partials) + bias + resid + LayerNorm ----
__global__ __launch_bounds__(256) void addbias3b_ln_kernel(float* __restrict__ dst,
                                                           const u16* __restrict__ p0,
                                                           const u16* __restrict__ p1,
                                                           const u16* __restrict__ p2,
                                                           const float* __restrict__ bias,
                                                           const float* __restrict__ resid,
                                                           const float* __restrict__ ga,
                                                           const float* __restrict__ gb,
                                                           u16* __restrict__ xn) {
    int row = blockIdx.x;
    int i4 = row * 256 + threadIdx.x;
    float4 d  = ((const float4*)dst)[i4];
    uint2 ua = ((const uint2*)p0)[i4];
    uint2 ub = ((const uint2*)p1)[i4];
    uint2 uc = ((const uint2*)p2)[i4];
    float4 rr = ((const float4*)resid)[i4];
    float4 bb = *(const float4*)(bias + threadIdx.x * 4);
    d.x += bf2f(ua.x) + bf2f(ub.x) + bf2f(uc.x) + bb.x + rr.x;
    d.y += bf2f_hi(ua.x) + bf2f_hi(ub.x) + bf2f_hi(uc.x) + bb.y + rr.y;
    d.z += bf2f(ua.y) + bf2f(ub.y) + bf2f(uc.y) + bb.z + rr.z;
    d.w += bf2f_hi(ua.y) + bf2f_hi(ub.y) + bf2f_hi(uc.y) + bb.w + rr.w;
    ((float4*)dst)[i4] = d;

    float s  = d.x + d.y + d.z + d.w;
    float s2 = d.x * d.x + d.y * d.y + d.z * d.z + d.w * d.w;
#pragma unroll
    for (int off = 32; off; off >>= 1) {
        s  += __shfl_down(s, off);
        s2 += __shfl_down(s2, off);
    }
    __shared__ float rs[4], rs2[4];
    int wid = threadIdx.x >> 6, lane = threadIdx.x & 63;
    if (lane == 0) { rs[wid] = s; rs2[wid] = s2; }
    __syncthreads();
    float S  = rs[0] + rs[1] + rs[2] + rs[3];
    float S2 = rs2[0] + rs2[1] + rs2[2] + rs2[3];
    float mean = S * (1.0f / 1024.0f);
    float var  = fmaxf((S2 - 1024.0f * mean * mean) * (1.0f / 1023.0f), 0.0f);
    float scale = ga[0] / (sqrtf(var) + 1e-6f);
    float shift = gb[0] - mean * scale;
    uint2 pv;
    pv.x = (u32)f2bf(d.x * scale + shift) | ((u32)f2bf(d.y * scale + shift) << 16);
    pv.y = (u32)f2bf(d.z * scale + shift) | ((u32)f2bf(d.w * scale + shift) << 16);
    *(uint2*)(xn + (size_t)row * 1024 + threadIdx.x * 4) = pv;
}

// ---------------- 256x256 8-wave GEMM, BK=64, 4-phase, swizzled LDS, counted vmcnt ----------------
// MODE 0: bf16 out + bias (+relu); biasB/biasC non-null => 3-way bias concat select (QKV).
// MODE 2: split-K via blockIdx.y; z<last -> bf16 partial to P[z]; z==last -> f32 to Cf.
template <int MODE, int RELU>
__global__ __launch_bounds__(512) void gemm256_bt(const u16* __restrict__ A,
                                                  const u16* __restrict__ Bt,
                                                  const float* __restrict__ bias,
                                                  const float* __restrict__ biasB,
                                                  const float* __restrict__ biasC,
                                                  u16* __restrict__ C,
                                                  u16* __restrict__ P0,
                                                  u16* __restrict__ P1,
                                                  u16* __restrict__ P2,
                                                  float* __restrict__ Cf,
                                                  int M, int N, int K, int tilesN, int kLen) {
    __shared__ u16 lds[2][2][16384];
    const int tid = threadIdx.x;
    const int lane = tid & 63, wid = tid >> 6;
    const int l15 = lane & 15, l4 = lane >> 4;
    const int wm = wid >> 2, wn = wid & 3;

    int nwg = gridDim.x;
    int bid = blockIdx.x;
    int swz = (bid & 7) * (nwg >> 3) + (bid >> 3);
    int ty = swz / tilesN, tx = swz % tilesN;
    const int kOff = blockIdx.y * kLen;

    const u16* Ag = A + (size_t)(ty * 256) * K;
    const u16* Bg = Bt + (size_t)(tx * 256) * K;

    auto stage_half = [&](int slot, int ab, int half, const u16* G, int k0) {
#pragma unroll
        for (int j = 0; j < 2; j++) {
            int off16 = half * 1024 + j * 512 + tid;
            int r = off16 >> 3;
            int gs = (off16 & 7) ^ (r & 7);
            const u16* src = G + (size_t)r * K + k0 + gs * 8;
            u16* dst = &lds[slot][ab][(size_t)(half * 1024 + j * 512 + (wid << 6)) * 8];
            async_load16(src, dst);
        }
    };

    f32x4 acc[8][4] = {};
    const int nT = kLen >> 6;

    stage_half(0, 0, 0, Ag, kOff);
    stage_half(0, 0, 1, Ag, kOff);
    stage_half(0, 1, 0, Bg, kOff);
    stage_half(0, 1, 1, Bg, kOff);
    __builtin_amdgcn_sched_barrier(0);

    for (int t = 0; t < nT; ++t) {
        const int cs = t & 1, ns = cs ^ 1;
        const int k1 = kOff + ((t + 1) << 6);
        const bool pf = (t + 1 < nT);
#pragma unroll
        for (int ph = 0; ph < 4; ++ph) {
            if (ph == 0 && pf) { stage_half(ns, 0, 0, Ag, k1); stage_half(ns, 0, 1, Ag, k1); }
            if (ph == 1 && pf) { stage_half(ns, 1, 0, Bg, k1); stage_half(ns, 1, 1, Bg, k1); }
            __builtin_amdgcn_sched_barrier(0);
            if (ph == 0) {
                if (pf) asm volatile("s_waitcnt vmcnt(4)" ::: "memory");
                else    asm volatile("s_waitcnt vmcnt(0)" ::: "memory");
            }
            wg_barrier();

            const int rh = ph >> 1, ch = ph & 1;
            const u16* la = &lds[cs][0][0];
            const u16* lb = &lds[cs][1][0];
            short8 af[4][2], bf[2][2];
#pragma unroll
            for (int m2 = 0; m2 < 4; m2++) {
                int ra = wm * 128 + rh * 64 + m2 * 16 + l15;
#pragma unroll
                for (int ks = 0; ks < 2; ks++) {
                    int sl = (l4 + ks * 4) ^ (ra & 7);
                    af[m2][ks] = *(const short8*)&la[ra * 64 + sl * 8];
                }
            }
#pragma unroll
            for (int n2 = 0; n2 < 2; n2++) {
                int rb = wn * 64 + ch * 32 + n2 * 16 + l15;
#pragma unroll
                for (int ks = 0; ks < 2; ks++) {
                    int sl = (l4 + ks * 4) ^ (rb & 7);
                    bf[n2][ks] = *(const short8*)&lb[rb * 64 + sl * 8];
                }
            }
            __builtin_amdgcn_s_setprio(1);
#pragma unroll
            for (int m2 = 0; m2 < 4; m2++)
#pragma unroll
                for (int n2 = 0; n2 < 2; n2++)
#pragma unroll
                    for (int ks = 0; ks < 2; ks++)
                        acc[rh * 4 + m2][ch * 2 + n2] = __builtin_amdgcn_mfma_f32_16x16x32_bf16(
                            af[m2][ks], bf[n2][ks], acc[rh * 4 + m2][ch * 2 + n2], 0, 0, 0);
            __builtin_amdgcn_s_setprio(0);
            wg_barrier();
        }
    }

    if (MODE == 0) {
#pragma unroll
        for (int mi = 0; mi < 8; mi++) {
            int row0 = ty * 256 + wm * 128 + (mi >> 2) * 64 + (mi & 3) * 16 + l4 * 4;
#pragma unroll
            for (int ni = 0; ni < 4; ni++) {
                int col = tx * 256 + wn * 64 + (ni >> 1) * 32 + (ni & 1) * 16 + l15;
                float bc;
                if (biasB) bc = (col < 1024) ? bias[col]
                               : (col < 2048) ? biasB[col - 1024] : biasC[col - 2048];
                else bc = bias[col];
#pragma unroll
                for (int jj = 0; jj < 4; jj++) {
                    float v = acc[mi][ni][jj] + bc;
                    if (RELU) v = fmaxf(v, 0.0f);
                    C[(size_t)(row0 + jj) * N + col] = f2bf(v);
                }
            }
        }
    } else {
        int z = blockIdx.y;
        bool last = (z == gridDim.y - 1);
        u16* P = (z == 0) ? P0 : (z == 1) ? P1 : P2;
#pragma unroll
        for (int mi = 0; mi < 8; mi++) {
            int row0 = ty * 256 + wm * 128 + (mi >> 2) * 64 + (mi & 3) * 16 + l4 * 4;
#pragma unroll
            for (int ni = 0; ni < 4; ni++) {
                int col = tx * 256 + wn * 64 + (ni >> 1) * 32 + (ni & 1) * 16 + l15;
#pragma unroll
                for (int jj = 0; jj < 4; jj++) {
                    float v = acc[mi][ni][jj];
                    if (last) Cf[(size_t)(row0 + jj) * N + col] = v;
                    else      P[(size_t)(row0 + jj) * N + col] = f2bf(v);
                }
            }
        }
    }
}

// ---------------- flash attention v6 (measured best): 8-wave split-S, PT-LDS P relayout ----------------
__global__ __launch_bounds__(512) void attn_kernel(const u16* __restrict__ qkv,
                                                   const u16* __restrict__ vT,
                                                   const int* __restrict__ mask,
                                                   u16* __restrict__ ctx) {
    const int S = 2048;
    const float C = 0.180336880f;  // 0.125 * log2(e)
    int qt = blockIdx.x;
    int bh = blockIdx.y;
    int b = bh >> 4, h = bh & 15;
    int tid = threadIdx.x;
    int wid = tid >> 6, lane = tid & 63;
    int l15 = lane & 15, l4 = lane >> 4;
    int g = wid >> 2, qw = wid & 3;

    __shared__ u16 Ks[2][64][72];
    __shared__ u16 Vs[2][64][72];
    __shared__ u32 PT[8][16][38];
    __shared__ float mbuf[2][4][16], lbuf[2][4][16];
    __shared__ int mflag;

    if (tid == 0) mflag = 1;
    __syncthreads();
    {
        const int* mrow = mask + b * S;
        int ok = 1;
#pragma unroll
        for (int i = 0; i < 4; i++) ok &= (mrow[tid * 4 + i] != 0);
        if (!ok) mflag = 0;
    }

    int qrow0 = qt * 64 + qw * 16;
    const u16* qb = qkv + (size_t)(b * S + qrow0) * 3072 + h * 64;
    short8 qf0 = *(const short8*)(qb + (size_t)l15 * 3072 + l4 * 8);
    short8 qf1 = *(const short8*)(qb + (size_t)l15 * 3072 + 32 + l4 * 8);

    f32x4 o[4] = {};
    float m_i = -1e30f, lp = 0.0f;
    __syncthreads();
    const int allones = mflag;
    const int* mrow = mask + b * S;

    int tl = tid & 255;
    int srow = tl >> 3, c8 = (tl & 7) * 8;
    const int kt0 = g * 16;
    short8 kreg[2], vreg[2];
#pragma unroll
    for (int p = 0; p < 2; p++) {
        int r = p * 32 + srow;
        kreg[p] = *(const short8*)(qkv + (size_t)(b * S + kt0 * 64 + r) * 3072 + 1024 + h * 64 + c8);
        vreg[p] = *(const short8*)(vT + (size_t)(bh * 64 + r) * 2048 + kt0 * 64 + c8);
    }

    for (int it = 0; it < 16; ++it) {
        const int kt = kt0 + it;
        wg_barrier();
#pragma unroll
        for (int p = 0; p < 2; p++) {
            int r = p * 32 + srow;
            *(short8*)&Ks[g][r][c8] = kreg[p];
            *(short8*)&Vs[g][r][c8] = vreg[p];
        }
        if (it + 1 < 16) {
#pragma unroll
            for (int p = 0; p < 2; p++) {
                int r = p * 32 + srow;
                kreg[p] = *(const short8*)(qkv + (size_t)(b * S + (kt + 1) * 64 + r) * 3072 + 1024 + h * 64 + c8);
                vreg[p] = *(const short8*)(vT + (size_t)(bh * 64 + r) * 2048 + (kt + 1) * 64 + c8);
            }
        }
        asm volatile("s_waitcnt lgkmcnt(0)" ::: "memory");
        wg_barrier();

        float sc[4][4];
#pragma unroll
        for (int kc = 0; kc < 4; kc++) {
            short8 kf0 = *(const short8*)&Ks[g][kc * 16 + l15][l4 * 8];
            short8 kf1 = *(const short8*)&Ks[g][kc * 16 + l15][32 + l4 * 8];
            f32x4 a = {};
            a = __builtin_amdgcn_mfma_f32_16x16x32_bf16(kf0, qf0, a, 0, 0, 0);
            a = __builtin_amdgcn_mfma_f32_16x16x32_bf16(kf1, qf1, a, 0, 0, 0);
            if (allones) {
#pragma unroll
                for (int j = 0; j < 4; j++) sc[kc][j] = a[j];
            } else {
#pragma unroll
                for (int j = 0; j < 4; j++) {
                    int mk = mrow[kt * 64 + kc * 16 + l4 * 4 + j];
                    sc[kc][j] = mk ? a[j] : -1e9f;
                }
            }
        }

        float lm = sc[0][0];
#pragma unroll
        for (int kc = 0; kc < 4; kc++)
#pragma unroll
            for (int j = 0; j < 4; j++) lm = fmaxf(lm, sc[kc][j]);
        if (!__all(lm <= m_i + 64.0f)) {
            float t = lm;
            t = fmaxf(t, __shfl_xor(t, 16));
            t = fmaxf(t, __shfl_xor(t, 32));
            float newm = fmaxf(m_i, t);
            float r = exp2fast((m_i - newm) * C);
            lp *= r;
            float rr0 = __shfl(r, l4 * 4 + 0);
            float rr1 = __shfl(r, l4 * 4 + 1);
            float rr2 = __shfl(r, l4 * 4 + 2);
            float rr3 = __shfl(r, l4 * 4 + 3);
#pragma unroll
            for (int dc = 0; dc < 4; dc++) {
                o[dc][0] *= rr0; o[dc][1] *= rr1; o[dc][2] *= rr2; o[dc][3] *= rr3;
            }
            m_i = newm;
        }

        float nb = -m_i * C;
#pragma unroll
        for (int kc = 0; kc < 4; kc++) {
            float p0 = exp2fast(fmaf(sc[kc][0], C, nb));
            float p1 = exp2fast(fmaf(sc[kc][1], C, nb));
            float p2 = exp2fast(fmaf(sc[kc][2], C, nb));
            float p3 = exp2fast(fmaf(sc[kc][3], C, nb));
            lp += (p0 + p1) + (p2 + p3);
            uint2 w;
            w.x = cvtpk(p0, p1);
            w.y = cvtpk(p2, p3);
            *(uint2*)&PT[wid][l15][kc * 8 + l4 * 2] = w;
        }

        uint2 r01 = *(const uint2*)&PT[wid][l15][l4 * 4];
        uint2 r23 = *(const uint2*)&PT[wid][l15][l4 * 4 + 2];
        uint2 r45 = *(const uint2*)&PT[wid][l15][16 + l4 * 4];
        uint2 r67 = *(const uint2*)&PT[wid][l15][16 + l4 * 4 + 2];
        u32x4 w0 = {r01.x, r01.y, r23.x, r23.y};
        u32x4 w1 = {r45.x, r45.y, r67.x, r67.y};
        short8 pa0 = __builtin_bit_cast(short8, w0);
        short8 pa1 = __builtin_bit_cast(short8, w1);

#pragma unroll
        for (int dc = 0; dc < 4; dc++) {
            short8 vf0 = *(const short8*)&Vs[g][dc * 16 + l15][l4 * 8];
            short8 vf1 = *(const short8*)&Vs[g][dc * 16 + l15][32 + l4 * 8];
            o[dc] = __builtin_amdgcn_mfma_f32_16x16x32_bf16(pa0, vf0, o[dc], 0, 0, 0);
            o[dc] = __builtin_amdgcn_mfma_f32_16x16x32_bf16(pa1, vf1, o[dc], 0, 0, 0);
        }
    }

    // -------- combine the two groups --------
    float lt = lp;
    lt += __shfl_xor(lt, 16);
    lt += __shfl_xor(lt, 32);
    if (l4 == 0) { mbuf[g][qw][l15] = m_i; lbuf[g][qw][l15] = lt; }
    __syncthreads();
    float mo = mbuf[g ^ 1][qw][l15], lo = lbuf[g ^ 1][qw][l15];
    float M  = fmaxf(m_i, mo);
    float rs = exp2fast((m_i - M) * C);
    float ro = exp2fast((mo - M) * C);
    float inv = 1.0f / (rs * lt + ro * lo);
    float rs_j[4], iv_j[4];
#pragma unroll
    for (int j = 0; j < 4; j++) {
        rs_j[j] = __shfl(rs,  l4 * 4 + j);
        iv_j[j] = __shfl(inv, l4 * 4 + j);
    }

    float* obuf = (float*)&Ks[0][0][0];  // 16 KB overlay on dead Ks
#pragma unroll
    for (int c = 0; c < 2; c++) {
        int dce = (g ^ 1) * 2 + c;
#pragma unroll
        for (int j = 0; j < 4; j++)
            obuf[(((g * 4 + qw) * 16) + l4 * 4 + j) * 32 + c * 16 + l15] = o[dce][j] * rs_j[j];
    }
    __syncthreads();
#pragma unroll
    for (int c = 0; c < 2; c++) {
        int dco = g * 2 + c;
#pragma unroll
        for (int j = 0; j < 4; j++) {
            float peer = obuf[((((g ^ 1) * 4 + qw) * 16) + l4 * 4 + j) * 32 + c * 16 + l15];
            float val = (o[dco][j] * rs_j[j] + peer) * iv_j[j];
            int row = qrow0 + l4 * 4 + j;
            ctx[(size_t)(b * S + row) * 1024 + h * 64 + dco * 16 + l15] = f2bf(val);
        }
    }
}

// ---------------- launcher ----------------
extern "C" void kernel_launch(void* const* d_in, const int* in_sizes, int n_in,
                              void* d_out, int out_size, void* d_ws, size_t ws_size,
                              hipStream_t stream) {
    const float* x    = (const float*)d_in[0];
    const int*   mask = (const int*)d_in[1];
    const float* wq   = (const float*)d_in[2];
    const float* bq   = (const float*)d_in[3];
    const float* wk   = (const float*)d_in[4];
    const float* bk   = (const float*)d_in[5];
    const float* wv   = (const float*)d_in[6];
    const float* bv   = (const float*)d_in[7];
    const float* wo   = (const float*)d_in[8];
    const float* bo   = (const float*)d_in[9];
    const float* w1   = (const float*)d_in[10];
    const float* b1   = (const float*)d_in[11];
    const float* w2   = (const float*)d_in[12];
    const float* b2   = (const float*)d_in[13];
    const float* ln1a = (const float*)d_in[14];
    const float* ln1b = (const float*)d_in[15];
    const float* ln2a = (const float*)d_in[16];
    const float* ln2b = (const float*)d_in[17];
    float* out = (float*)d_out;

    char* ws = (char*)d_ws;
    u16*   wqkvt = (u16*)(ws + 0);            //  6 MB (dead after QKV)
    u16*   wot   = (u16*)(ws + 6291456);      //  2 MB (dead after WO)
    u16*   w1t   = (u16*)(ws + 8388608);      //  8 MB (dead after FFN1)
    u16*   w2t   = (u16*)(ws + 16777216);     //  8 MB (live through FFN2)
    char*  regA  = ws + 26214400;
    u16*   xn1   = (u16*)(regA + 0);          //  8 MB
    u16*   vT    = (u16*)(regA + 0);          //  8 MB (aliases xn1; dead after attn)
    u16*   qkv   = (u16*)(regA + 8388608);    // 24 MB (dead after attn)
    u16*   ctx   = (u16*)(regA + 33554432);   //  8 MB (dead after WO)
    // WO bf16 partials (over dead qkv region):
    u16*   pw0   = (u16*)(regA + 8388608);    //  8 MB
    u16*   pw1   = (u16*)(regA + 16777216);   //  8 MB
    u16*   pw2   = (u16*)(regA + 25165824);   //  8 MB
    float* x1    = (float*)(ws + 68157440);   // 16 MB
    u16*   xn2   = (u16*)(regA + 0);          //  8 MB
    u16*   ff1   = (u16*)(regA + 8388608);    // 32 MB
    // FFN2 bf16 partials:
    u16*   pb0   = (u16*)(ws + 0);            //  8 MB (over wqkvt+wot)
    u16*   pb1   = (u16*)(ws + 8388608);      //  8 MB (over w1t)
    u16*   pb2   = (u16*)(regA + 0);          //  8 MB (over xn2, dead after FFN1)

    dim3 blk(256);

    convt64x4_kernel<<<dim3(16, 16, 4), blk, 0, stream>>>(
        wq, wk, wv, wo, wqkvt, wqkvt + 1024 * 1024, wqkvt + 2048 * 1024, wot);
    convt64_kernel<<<dim3(64, 16), blk, 0, stream>>>(w1, w1t, 1024, 4096);
    convt64_kernel<<<dim3(16, 64), blk, 0, stream>>>(w2, w2t, 4096, 1024);

    // LN1 -> QKV (256^2 8-wave, 3-way bias) -> attn -> WO (256^2 split-K=4) + reduce+bo+x+LN2
    ln_kernel<<<dim3(4096), blk, 0, stream>>>(x, ln1a, ln1b, xn1);
    gemm256_bt<0, 0><<<dim3(192, 1), dim3(512), 0, stream>>>(
        xn1, wqkvt, bq, bk, bv, qkv, nullptr, nullptr, nullptr, nullptr, 4096, 3072, 1024, 12, 1024);
    vtrans64_kernel<<<dim3(32, 16, 2), blk, 0, stream>>>(qkv, vT);
    attn_kernel<<<dim3(32, 32), dim3(512), 0, stream>>>(qkv, vT, mask, ctx);
    gemm256_bt<2, 0><<<dim3(64, 4), dim3(512), 0, stream>>>(
        ctx, wot, nullptr, nullptr, nullptr, nullptr, pw0, pw1, pw2, x1, 4096, 1024, 1024, 4, 256);
    addbias3b_ln_kernel<<<dim3(4096), blk, 0, stream>>>(x1, pw0, pw1, pw2, bo, x, ln2a, ln2b, xn2);

    // FFN1 (256^2 8-wave, relu) -> FFN2 (256^2 8-wave, split-K=4) + reduce(+b2+x1)
    gemm256_bt<0, 1><<<dim3(256, 1), dim3(512), 0, stream>>>(
        xn2, w1t, b1, nullptr, nullptr, ff1, nullptr, nullptr, nullptr, nullptr, 4096, 4096, 1024, 16, 1024);
    gemm256_bt<2, 0><<<dim3(64, 4), dim3(512), 0, stream>>>(
        ff1, w2t, nullptr, nullptr, nullptr, nullptr, pb0, pb1, pb2, out, 4096, 1024, 4096, 4, 1024);
    addbias3b_kernel<<<dim3(4096), blk, 0, stream>>>(out, pb0, pb1, pb2, b2, x1);
}

// Round 14
// 263.021 us; speedup vs baseline: 1.0173x; 1.0173x over previous
//
#include <hip/hip_runtime.h>
#include <hip/hip_bf16.h>

typedef __attribute__((ext_vector_type(8))) short short8;
typedef __attribute__((ext_vector_type(4))) float f32x4;
typedef __attribute__((ext_vector_type(4))) unsigned int u32x4;
using u16 = unsigned short;
typedef unsigned int u32;

__device__ __forceinline__ u16 f2bf(float f) {
    u32 u = __builtin_bit_cast(u32, f);
    u32 r = u + 0x7FFFu + ((u >> 16) & 1u);
    return (u16)(r >> 16);
}

__device__ __forceinline__ float bf2f(u32 w) {  // low 16 bits = bf16
    return __builtin_bit_cast(float, w << 16);
}
__device__ __forceinline__ float bf2f_hi(u32 w) {
    return __builtin_bit_cast(float, w & 0xFFFF0000u);
}

__device__ __forceinline__ float exp2fast(float x) {
    return __builtin_amdgcn_exp2f(x);  // v_exp_f32
}

__device__ __forceinline__ u32 cvtpk(float lo, float hi) {
    u32 r;
    asm("v_cvt_pk_bf16_f32 %0, %1, %2" : "=v"(r) : "v"(lo), "v"(hi));
    return r;
}

__device__ __forceinline__ void async_load16(const void* g, void* l) {
    __builtin_amdgcn_global_load_lds(
        (const __attribute__((address_space(1))) void*)g,
        (__attribute__((address_space(3))) void*)l, 16, 0, 0);
}

__device__ __forceinline__ void wg_barrier() {
    asm volatile("" ::: "memory");
    __builtin_amdgcn_s_barrier();
    asm volatile("" ::: "memory");
}

// ---------------- weight transpose + f32->bf16 convert: w[K][N] -> wt[N][K] ----------------
__global__ __launch_bounds__(256) void convt_kernel(const float* __restrict__ w,
                                                    u16* __restrict__ wt, int K, int N) {
    __shared__ float tile[32][33];
    int bn = blockIdx.x * 32, bk = blockIdx.y * 32;
    int tx = threadIdx.x & 31, ty = threadIdx.x >> 5;
#pragma unroll
    for (int i = 0; i < 4; i++)
        tile[ty + i * 8][tx] = w[(size_t)(bk + ty + i * 8) * N + bn + tx];
    __syncthreads();
#pragma unroll
    for (int i = 0; i < 4; i++)
        wt[(size_t)(bn + ty + i * 8) * K + bk + tx] = f2bf(tile[tx][ty + i * 8]);
}

// 4 square 1024x1024 transposes in one launch
__global__ __launch_bounds__(256) void convt4_kernel(const float* __restrict__ wa,
                                                     const float* __restrict__ wb,
                                                     const float* __restrict__ wc,
                                                     const float* __restrict__ wd,
                                                     u16* __restrict__ da,
                                                     u16* __restrict__ db,
                                                     u16* __restrict__ dc,
                                                     u16* __restrict__ dd) {
    __shared__ float tile[32][33];
    int z = blockIdx.z;
    const float* w = (z == 0) ? wa : (z == 1) ? wb : (z == 2) ? wc : wd;
    u16* wt = (z == 0) ? da : (z == 1) ? db : (z == 2) ? dc : dd;
    int bn = blockIdx.x * 32, bk = blockIdx.y * 32;
    int tx = threadIdx.x & 31, ty = threadIdx.x >> 5;
#pragma unroll
    for (int i = 0; i < 4; i++)
        tile[ty + i * 8][tx] = w[(size_t)(bk + ty + i * 8) * 1024 + bn + tx];
    __syncthreads();
#pragma unroll
    for (int i = 0; i < 4; i++)
        wt[(size_t)(bn + ty + i * 8) * 1024 + bk + tx] = f2bf(tile[tx][ty + i * 8]);
}

// ---------------- V transpose (bf16): qkv V-part [b][s][1024] -> vT[b*1024+col][2048] ----------------
__global__ __launch_bounds__(256) void vtrans_kernel(const u16* __restrict__ qkv,
                                                     u16* __restrict__ vT) {
    __shared__ u16 tile[32][33];
    int bs = blockIdx.x * 32;
    int bc = blockIdx.y * 32;
    int b  = blockIdx.z;
    int tx = threadIdx.x & 31, ty = threadIdx.x >> 5;
#pragma unroll
    for (int i = 0; i < 4; i++)
        tile[ty + i * 8][tx] = qkv[(size_t)(b * 2048 + bs + ty + i * 8) * 3072 + 2048 + bc + tx];
    __syncthreads();
#pragma unroll
    for (int i = 0; i < 4; i++)
        vT[(size_t)(b * 1024 + bc + ty + i * 8) * 2048 + bs + tx] = tile[tx][ty + i * 8];
}

// ---------------- LayerNorm (fp32 in, bf16 out) ----------------
__global__ __launch_bounds__(256) void ln_kernel(const float* __restrict__ x,
                                                 const float* __restrict__ ga,
                                                 const float* __restrict__ gb,
                                                 u16* __restrict__ out) {
    int row = blockIdx.x;
    const float4* xr = (const float4*)(x + (size_t)row * 1024);
    float4 v = xr[threadIdx.x];
    float s  = v.x + v.y + v.z + v.w;
    float s2 = v.x * v.x + v.y * v.y + v.z * v.z + v.w * v.w;
#pragma unroll
    for (int off = 32; off; off >>= 1) {
        s  += __shfl_down(s, off);
        s2 += __shfl_down(s2, off);
    }
    __shared__ float rs[4], rs2[4];
    int wid = threadIdx.x >> 6, lane = threadIdx.x & 63;
    if (lane == 0) { rs[wid] = s; rs2[wid] = s2; }
    __syncthreads();
    float S  = rs[0] + rs[1] + rs[2] + rs[3];
    float S2 = rs2[0] + rs2[1] + rs2[2] + rs2[3];
    float mean = S * (1.0f / 1024.0f);
    float var  = fmaxf((S2 - 1024.0f * mean * mean) * (1.0f / 1023.0f), 0.0f);
    float scale = ga[0] / (sqrtf(var) + 1e-6f);
    float shift = gb[0] - mean * scale;
    u16 h0 = f2bf(v.x * scale + shift);
    u16 h1 = f2bf(v.y * scale + shift);
    u16 h2 = f2bf(v.z * scale + shift);
    u16 h3 = f2bf(v.w * scale + shift);
    uint2 pv;
    pv.x = (u32)h0 | ((u32)h1 << 16);
    pv.y = (u32)h2 | ((u32)h3 << 16);
    *(uint2*)(out + (size_t)row * 1024 + threadIdx.x * 4) = pv;
}

// ---------------- bias concat ----------------
__global__ __launch_bounds__(256) void bias3_kernel(const float* __restrict__ a,
                                                    const float* __restrict__ b,
                                                    const float* __restrict__ c,
                                                    float* __restrict__ d) {
    int i = blockIdx.x * 256 + threadIdx.x;
    float v = (i < 1024) ? a[i] : ((i < 2048) ? b[i - 1024] : c[i - 2048]);
    d[i] = v;
}

// ---- fused reduce (3 bf16 partials): dst = dst + p0 + p1 + p2 + bias + resid ----
__global__ __launch_bounds__(256) void addbias3b_kernel(float* __restrict__ dst,
                                                        const u16* __restrict__ p0,
                                                        const u16* __restrict__ p1,
                                                        const u16* __restrict__ p2,
                                                        const float* __restrict__ bias,
                                                        const float* __restrict__ resid) {
    int i4 = blockIdx.x * 256 + threadIdx.x;
    float4 d  = ((const float4*)dst)[i4];
    uint2 ua = ((const uint2*)p0)[i4];
    uint2 ub = ((const uint2*)p1)[i4];
    uint2 uc = ((const uint2*)p2)[i4];
    float4 rr = ((const float4*)resid)[i4];
    float4 bb = *(const float4*)(bias + ((i4 * 4) & 1023));
    d.x += bf2f(ua.x) + bf2f(ub.x) + bf2f(uc.x) + bb.x + rr.x;
    d.y += bf2f_hi(ua.x) + bf2f_hi(ub.x) + bf2f_hi(uc.x) + bb.y + rr.y;
    d.z += bf2f(ua.y) + bf2f(ub.y) + bf2f(uc.y) + bb.z + rr.z;
    d.w += bf2f_hi(ua.y) + bf2f_hi(ub.y) + bf2f_hi(uc.y) + bb.w + rr.w;
    ((float4*)dst)[i4] = d;
}

// ---- fused reduce (3 bf16 partials) + bias + resid + LayerNorm: x1, xn = LN(x1) bf16 ----
// one block per row of 1024 (grid 4096 x 256 thr)
__global__ __launch_bounds__(256) void addbias3b_ln_kernel(float* __restrict__ dst,
                                                           const u16* __restrict__ p0,
                                                           const u16* __restrict__ p1,
                                                           const u16* __restrict__ p2,
                                                           const float* __restrict__ bias,
                                                           const float* __restrict__ resid,
                                                           const float* __restrict__ ga,
                                                           const float* __restrict__ gb,
                                                           u16* __restrict__ xn) {
    int row = blockIdx.x;
    int i4 = row * 256 + threadIdx.x;
    float4 d  = ((const float4*)dst)[i4];
    uint2 ua = ((const uint2*)p0)[i4];
    uint2 ub = ((const uint2*)p1)[i4];
    uint2 uc = ((const uint2*)p2)[i4];
    float4 rr = ((const float4*)resid)[i4];
    float4 bb = *(const float4*)(bias + threadIdx.x * 4);
    d.x += bf2f(ua.x) + bf2f(ub.x) + bf2f(uc.x) + bb.x + rr.x;
    d.y += bf2f_hi(ua.x) + bf2f_hi(ub.x) + bf2f_hi(uc.x) + bb.y + rr.y;
    d.z += bf2f(ua.y) + bf2f(ub.y) + bf2f(uc.y) + bb.z + rr.z;
    d.w += bf2f_hi(ua.y) + bf2f_hi(ub.y) + bf2f_hi(uc.y) + bb.w + rr.w;
    ((float4*)dst)[i4] = d;

    float s  = d.x + d.y + d.z + d.w;
    float s2 = d.x * d.x + d.y * d.y + d.z * d.z + d.w * d.w;
#pragma unroll
    for (int off = 32; off; off >>= 1) {
        s  += __shfl_down(s, off);
        s2 += __shfl_down(s2, off);
    }
    __shared__ float rs[4], rs2[4];
    int wid = threadIdx.x >> 6, lane = threadIdx.x & 63;
    if (lane == 0) { rs[wid] = s; rs2[wid] = s2; }
    __syncthreads();
    float S  = rs[0] + rs[1] + rs[2] + rs[3];
    float S2 = rs2[0] + rs2[1] + rs2[2] + rs2[3];
    float mean = S * (1.0f / 1024.0f);
    float var  = fmaxf((S2 - 1024.0f * mean * mean) * (1.0f / 1023.0f), 0.0f);
    float scale = ga[0] / (sqrtf(var) + 1e-6f);
    float shift = gb[0] - mean * scale;
    uint2 pv;
    pv.x = (u32)f2bf(d.x * scale + shift) | ((u32)f2bf(d.y * scale + shift) << 16);
    pv.y = (u32)f2bf(d.z * scale + shift) | ((u32)f2bf(d.w * scale + shift) << 16);
    *(uint2*)(xn + (size_t)row * 1024 + threadIdx.x * 4) = pv;
}

// ---------------- 256x256 8-wave GEMM, BK=64, 4-phase, swizzled LDS, counted vmcnt ----------------
// MODE 0: bf16 out + bias (+relu). MODE 2: split-K via blockIdx.y (kLen per split);
//   z < gridDim.y-1 -> bf16 partial to P[z]; z == gridDim.y-1 -> f32 partial to Cf.
template <int MODE, int RELU>
__global__ __launch_bounds__(512) void gemm256_bt(const u16* __restrict__ A,
                                                  const u16* __restrict__ Bt,
                                                  const float* __restrict__ bias,
                                                  u16* __restrict__ C,
                                                  u16* __restrict__ P0,
                                                  u16* __restrict__ P1,
                                                  u16* __restrict__ P2,
                                                  float* __restrict__ Cf,
                                                  int M, int N, int K, int tilesN, int kLen) {
    __shared__ u16 lds[2][2][16384];
    const int tid = threadIdx.x;
    const int lane = tid & 63, wid = tid >> 6;
    const int l15 = lane & 15, l4 = lane >> 4;
    const int wm = wid >> 2, wn = wid & 3;

    int nwg = gridDim.x;
    int bid = blockIdx.x;
    int swz = (bid & 7) * (nwg >> 3) + (bid >> 3);
    int ty = swz / tilesN, tx = swz % tilesN;
    const int kOff = blockIdx.y * kLen;

    const u16* Ag = A + (size_t)(ty * 256) * K;
    const u16* Bg = Bt + (size_t)(tx * 256) * K;

    auto stage_half = [&](int slot, int ab, int half, const u16* G, int k0) {
#pragma unroll
        for (int j = 0; j < 2; j++) {
            int off16 = half * 1024 + j * 512 + tid;
            int r = off16 >> 3;
            int gs = (off16 & 7) ^ (r & 7);
            const u16* src = G + (size_t)r * K + k0 + gs * 8;
            u16* dst = &lds[slot][ab][(size_t)(half * 1024 + j * 512 + (wid << 6)) * 8];
            async_load16(src, dst);
        }
    };

    f32x4 acc[8][4] = {};
    const int nT = kLen >> 6;

    stage_half(0, 0, 0, Ag, kOff);
    stage_half(0, 0, 1, Ag, kOff);
    stage_half(0, 1, 0, Bg, kOff);
    stage_half(0, 1, 1, Bg, kOff);
    __builtin_amdgcn_sched_barrier(0);

    for (int t = 0; t < nT; ++t) {
        const int cs = t & 1, ns = cs ^ 1;
        const int k1 = kOff + ((t + 1) << 6);
        const bool pf = (t + 1 < nT);
#pragma unroll
        for (int ph = 0; ph < 4; ++ph) {
            if (ph == 0 && pf) { stage_half(ns, 0, 0, Ag, k1); stage_half(ns, 0, 1, Ag, k1); }
            if (ph == 1 && pf) { stage_half(ns, 1, 0, Bg, k1); stage_half(ns, 1, 1, Bg, k1); }
            __builtin_amdgcn_sched_barrier(0);
            if (ph == 0) {
                if (pf) asm volatile("s_waitcnt vmcnt(4)" ::: "memory");
                else    asm volatile("s_waitcnt vmcnt(0)" ::: "memory");
            }
            wg_barrier();

            const int rh = ph >> 1, ch = ph & 1;
            const u16* la = &lds[cs][0][0];
            const u16* lb = &lds[cs][1][0];
            short8 af[4][2], bf[2][2];
#pragma unroll
            for (int m2 = 0; m2 < 4; m2++) {
                int ra = wm * 128 + rh * 64 + m2 * 16 + l15;
#pragma unroll
                for (int ks = 0; ks < 2; ks++) {
                    int sl = (l4 + ks * 4) ^ (ra & 7);
                    af[m2][ks] = *(const short8*)&la[ra * 64 + sl * 8];
                }
            }
#pragma unroll
            for (int n2 = 0; n2 < 2; n2++) {
                int rb = wn * 64 + ch * 32 + n2 * 16 + l15;
#pragma unroll
                for (int ks = 0; ks < 2; ks++) {
                    int sl = (l4 + ks * 4) ^ (rb & 7);
                    bf[n2][ks] = *(const short8*)&lb[rb * 64 + sl * 8];
                }
            }
            __builtin_amdgcn_s_setprio(1);
#pragma unroll
            for (int m2 = 0; m2 < 4; m2++)
#pragma unroll
                for (int n2 = 0; n2 < 2; n2++)
#pragma unroll
                    for (int ks = 0; ks < 2; ks++)
                        acc[rh * 4 + m2][ch * 2 + n2] = __builtin_amdgcn_mfma_f32_16x16x32_bf16(
                            af[m2][ks], bf[n2][ks], acc[rh * 4 + m2][ch * 2 + n2], 0, 0, 0);
            __builtin_amdgcn_s_setprio(0);
            wg_barrier();
        }
    }

    if (MODE == 0) {
#pragma unroll
        for (int mi = 0; mi < 8; mi++) {
            int row0 = ty * 256 + wm * 128 + (mi >> 2) * 64 + (mi & 3) * 16 + l4 * 4;
#pragma unroll
            for (int ni = 0; ni < 4; ni++) {
                int col = tx * 256 + wn * 64 + (ni >> 1) * 32 + (ni & 1) * 16 + l15;
                float bc = bias[col];
#pragma unroll
                for (int jj = 0; jj < 4; jj++) {
                    float v = acc[mi][ni][jj] + bc;
                    if (RELU) v = fmaxf(v, 0.0f);
                    C[(size_t)(row0 + jj) * N + col] = f2bf(v);
                }
            }
        }
    } else {
        int z = blockIdx.y;
        bool last = (z == gridDim.y - 1);
        u16* P = (z == 0) ? P0 : (z == 1) ? P1 : P2;
#pragma unroll
        for (int mi = 0; mi < 8; mi++) {
            int row0 = ty * 256 + wm * 128 + (mi >> 2) * 64 + (mi & 3) * 16 + l4 * 4;
#pragma unroll
            for (int ni = 0; ni < 4; ni++) {
                int col = tx * 256 + wn * 64 + (ni >> 1) * 32 + (ni & 1) * 16 + l15;
#pragma unroll
                for (int jj = 0; jj < 4; jj++) {
                    float v = acc[mi][ni][jj];
                    if (last) Cf[(size_t)(row0 + jj) * N + col] = v;
                    else      P[(size_t)(row0 + jj) * N + col] = f2bf(v);
                }
            }
        }
    }
}

// ---------------- flash attention v6 (measured best): 8-wave split-S, PT-LDS P relayout ----------------
__global__ __launch_bounds__(512) void attn_kernel(const u16* __restrict__ qkv,
                                                   const u16* __restrict__ vT,
                                                   const int* __restrict__ mask,
                                                   u16* __restrict__ ctx) {
    const int S = 2048;
    const float C = 0.180336880f;  // 0.125 * log2(e)
    int qt = blockIdx.x;
    int bh = blockIdx.y;
    int b = bh >> 4, h = bh & 15;
    int tid = threadIdx.x;
    int wid = tid >> 6, lane = tid & 63;
    int l15 = lane & 15, l4 = lane >> 4;
    int g = wid >> 2, qw = wid & 3;

    __shared__ u16 Ks[2][64][72];
    __shared__ u16 Vs[2][64][72];
    __shared__ u32 PT[8][16][38];
    __shared__ float mbuf[2][4][16], lbuf[2][4][16];
    __shared__ int mflag;

    if (tid == 0) mflag = 1;
    __syncthreads();
    {
        const int* mrow = mask + b * S;
        int ok = 1;
#pragma unroll
        for (int i = 0; i < 4; i++) ok &= (mrow[tid * 4 + i] != 0);
        if (!ok) mflag = 0;
    }

    int qrow0 = qt * 64 + qw * 16;
    const u16* qb = qkv + (size_t)(b * S + qrow0) * 3072 + h * 64;
    short8 qf0 = *(const short8*)(qb + (size_t)l15 * 3072 + l4 * 8);
    short8 qf1 = *(const short8*)(qb + (size_t)l15 * 3072 + 32 + l4 * 8);

    f32x4 o[4] = {};
    float m_i = -1e30f, lp = 0.0f;
    __syncthreads();
    const int allones = mflag;
    const int* mrow = mask + b * S;

    int tl = tid & 255;
    int srow = tl >> 3, c8 = (tl & 7) * 8;
    const int kt0 = g * 16;
    short8 kreg[2], vreg[2];
#pragma unroll
    for (int p = 0; p < 2; p++) {
        int r = p * 32 + srow;
        kreg[p] = *(const short8*)(qkv + (size_t)(b * S + kt0 * 64 + r) * 3072 + 1024 + h * 64 + c8);
        vreg[p] = *(const short8*)(vT + (size_t)(bh * 64 + r) * 2048 + kt0 * 64 + c8);
    }

    for (int it = 0; it < 16; ++it) {
        const int kt = kt0 + it;
        wg_barrier();
#pragma unroll
        for (int p = 0; p < 2; p++) {
            int r = p * 32 + srow;
            *(short8*)&Ks[g][r][c8] = kreg[p];
            *(short8*)&Vs[g][r][c8] = vreg[p];
        }
        if (it + 1 < 16) {
#pragma unroll
            for (int p = 0; p < 2; p++) {
                int r = p * 32 + srow;
                kreg[p] = *(const short8*)(qkv + (size_t)(b * S + (kt + 1) * 64 + r) * 3072 + 1024 + h * 64 + c8);
                vreg[p] = *(const short8*)(vT + (size_t)(bh * 64 + r) * 2048 + (kt + 1) * 64 + c8);
            }
        }
        asm volatile("s_waitcnt lgkmcnt(0)" ::: "memory");
        wg_barrier();

        float sc[4][4];
#pragma unroll
        for (int kc = 0; kc < 4; kc++) {
            short8 kf0 = *(const short8*)&Ks[g][kc * 16 + l15][l4 * 8];
            short8 kf1 = *(const short8*)&Ks[g][kc * 16 + l15][32 + l4 * 8];
            f32x4 a = {};
            a = __builtin_amdgcn_mfma_f32_16x16x32_bf16(kf0, qf0, a, 0, 0, 0);
            a = __builtin_amdgcn_mfma_f32_16x16x32_bf16(kf1, qf1, a, 0, 0, 0);
            if (allones) {
#pragma unroll
                for (int j = 0; j < 4; j++) sc[kc][j] = a[j];
            } else {
#pragma unroll
                for (int j = 0; j < 4; j++) {
                    int mk = mrow[kt * 64 + kc * 16 + l4 * 4 + j];
                    sc[kc][j] = mk ? a[j] : -1e9f;
                }
            }
        }

        float lm = sc[0][0];
#pragma unroll
        for (int kc = 0; kc < 4; kc++)
#pragma unroll
            for (int j = 0; j < 4; j++) lm = fmaxf(lm, sc[kc][j]);
        if (!__all(lm <= m_i + 64.0f)) {
            float t = lm;
            t = fmaxf(t, __shfl_xor(t, 16));
            t = fmaxf(t, __shfl_xor(t, 32));
            float newm = fmaxf(m_i, t);
            float r = exp2fast((m_i - newm) * C);
            lp *= r;
            float rr0 = __shfl(r, l4 * 4 + 0);
            float rr1 = __shfl(r, l4 * 4 + 1);
            float rr2 = __shfl(r, l4 * 4 + 2);
            float rr3 = __shfl(r, l4 * 4 + 3);
#pragma unroll
            for (int dc = 0; dc < 4; dc++) {
                o[dc][0] *= rr0; o[dc][1] *= rr1; o[dc][2] *= rr2; o[dc][3] *= rr3;
            }
            m_i = newm;
        }

        float nb = -m_i * C;
#pragma unroll
        for (int kc = 0; kc < 4; kc++) {
            float p0 = exp2fast(fmaf(sc[kc][0], C, nb));
            float p1 = exp2fast(fmaf(sc[kc][1], C, nb));
            float p2 = exp2fast(fmaf(sc[kc][2], C, nb));
            float p3 = exp2fast(fmaf(sc[kc][3], C, nb));
            lp += (p0 + p1) + (p2 + p3);
            uint2 w;
            w.x = cvtpk(p0, p1);
            w.y = cvtpk(p2, p3);
            *(uint2*)&PT[wid][l15][kc * 8 + l4 * 2] = w;
        }

        uint2 r01 = *(const uint2*)&PT[wid][l15][l4 * 4];
        uint2 r23 = *(const uint2*)&PT[wid][l15][l4 * 4 + 2];
        uint2 r45 = *(const uint2*)&PT[wid][l15][16 + l4 * 4];
        uint2 r67 = *(const uint2*)&PT[wid][l15][16 + l4 * 4 + 2];
        u32x4 w0 = {r01.x, r01.y, r23.x, r23.y};
        u32x4 w1 = {r45.x, r45.y, r67.x, r67.y};
        short8 pa0 = __builtin_bit_cast(short8, w0);
        short8 pa1 = __builtin_bit_cast(short8, w1);

#pragma unroll
        for (int dc = 0; dc < 4; dc++) {
            short8 vf0 = *(const short8*)&Vs[g][dc * 16 + l15][l4 * 8];
            short8 vf1 = *(const short8*)&Vs[g][dc * 16 + l15][32 + l4 * 8];
            o[dc] = __builtin_amdgcn_mfma_f32_16x16x32_bf16(pa0, vf0, o[dc], 0, 0, 0);
            o[dc] = __builtin_amdgcn_mfma_f32_16x16x32_bf16(pa1, vf1, o[dc], 0, 0, 0);
        }
    }

    // -------- combine the two groups --------
    float lt = lp;
    lt += __shfl_xor(lt, 16);
    lt += __shfl_xor(lt, 32);
    if (l4 == 0) { mbuf[g][qw][l15] = m_i; lbuf[g][qw][l15] = lt; }
    __syncthreads();
    float mo = mbuf[g ^ 1][qw][l15], lo = lbuf[g ^ 1][qw][l15];
    float M  = fmaxf(m_i, mo);
    float rs = exp2fast((m_i - M) * C);
    float ro = exp2fast((mo - M) * C);
    float inv = 1.0f / (rs * lt + ro * lo);
    float rs_j[4], iv_j[4];
#pragma unroll
    for (int j = 0; j < 4; j++) {
        rs_j[j] = __shfl(rs,  l4 * 4 + j);
        iv_j[j] = __shfl(inv, l4 * 4 + j);
    }

    float* obuf = (float*)&Ks[0][0][0];  // 16 KB overlay on dead Ks
#pragma unroll
    for (int c = 0; c < 2; c++) {
        int dce = (g ^ 1) * 2 + c;
#pragma unroll
        for (int j = 0; j < 4; j++)
            obuf[(((g * 4 + qw) * 16) + l4 * 4 + j) * 32 + c * 16 + l15] = o[dce][j] * rs_j[j];
    }
    __syncthreads();
#pragma unroll
    for (int c = 0; c < 2; c++) {
        int dco = g * 2 + c;
#pragma unroll
        for (int j = 0; j < 4; j++) {
            float peer = obuf[((((g ^ 1) * 4 + qw) * 16) + l4 * 4 + j) * 32 + c * 16 + l15];
            float val = (o[dco][j] * rs_j[j] + peer) * iv_j[j];
            int row = qrow0 + l4 * 4 + j;
            ctx[(size_t)(b * S + row) * 1024 + h * 64 + dco * 16 + l15] = f2bf(val);
        }
    }
}

// ---------------- launcher ----------------
extern "C" void kernel_launch(void* const* d_in, const int* in_sizes, int n_in,
                              void* d_out, int out_size, void* d_ws, size_t ws_size,
                              hipStream_t stream) {
    const float* x    = (const float*)d_in[0];
    const int*   mask = (const int*)d_in[1];
    const float* wq   = (const float*)d_in[2];
    const float* bq   = (const float*)d_in[3];
    const float* wk   = (const float*)d_in[4];
    const float* bk   = (const float*)d_in[5];
    const float* wv   = (const float*)d_in[6];
    const float* bv   = (const float*)d_in[7];
    const float* wo   = (const float*)d_in[8];
    const float* bo   = (const float*)d_in[9];
    const float* w1   = (const float*)d_in[10];
    const float* b1   = (const float*)d_in[11];
    const float* w2   = (const float*)d_in[12];
    const float* b2   = (const float*)d_in[13];
    const float* ln1a = (const float*)d_in[14];
    const float* ln1b = (const float*)d_in[15];
    const float* ln2a = (const float*)d_in[16];
    const float* ln2b = (const float*)d_in[17];
    float* out = (float*)d_out;

    char* ws = (char*)d_ws;
    u16*   wqkvt = (u16*)(ws + 0);            //  6 MB (dead after QKV)
    u16*   wot   = (u16*)(ws + 6291456);      //  2 MB (dead after WO)
    u16*   w1t   = (u16*)(ws + 8388608);      //  8 MB (dead after FFN1)
    u16*   w2t   = (u16*)(ws + 16777216);     //  8 MB (live through FFN2)
    float* bqkv  = (float*)(ws + 25165824);   // 12 KB
    char*  regA  = ws + 26214400;
    u16*   xn1   = (u16*)(regA + 0);          //  8 MB
    u16*   vT    = (u16*)(regA + 0);          //  8 MB (aliases xn1; dead after attn)
    u16*   qkv   = (u16*)(regA + 8388608);    // 24 MB (dead after attn)
    u16*   ctx   = (u16*)(regA + 33554432);   //  8 MB (dead after WO)
    // WO bf16 partials (over dead qkv region):
    u16*   pw0   = (u16*)(regA + 8388608);    //  8 MB
    u16*   pw1   = (u16*)(regA + 16777216);   //  8 MB
    u16*   pw2   = (u16*)(regA + 25165824);   //  8 MB
    float* x1    = (float*)(ws + 68157440);   // 16 MB
    u16*   xn2   = (u16*)(regA + 0);          //  8 MB (vT dead; WO partials dead after reduce)
    u16*   ff1   = (u16*)(regA + 8388608);    // 32 MB (pw* + ctx dead by FFN1 time)
    // FFN2 bf16 partials (dead regions by FFN2 time):
    u16*   pb0   = (u16*)(ws + 0);            //  8 MB (over wqkvt+wot)
    u16*   pb1   = (u16*)(ws + 8388608);      //  8 MB (over w1t)
    u16*   pb2   = (u16*)(regA + 0);          //  8 MB (over xn2, dead after FFN1)

    dim3 blk(256);

    convt4_kernel<<<dim3(32, 32, 4), blk, 0, stream>>>(
        wq, wk, wv, wo, wqkvt, wqkvt + 1024 * 1024, wqkvt + 2048 * 1024, wot);
    convt_kernel<<<dim3(128, 32), blk, 0, stream>>>(w1, w1t, 1024, 4096);
    convt_kernel<<<dim3(32, 128), blk, 0, stream>>>(w2, w2t, 4096, 1024);
    bias3_kernel<<<dim3(12), blk, 0, stream>>>(bq, bk, bv, bqkv);

    // LN1 -> QKV (256^2 8-wave) -> attn -> WO (256^2 split-K=4) + fused reduce+bo+x+LN2
    ln_kernel<<<dim3(4096), blk, 0, stream>>>(x, ln1a, ln1b, xn1);
    gemm256_bt<0, 0><<<dim3(192, 1), dim3(512), 0, stream>>>(
        xn1, wqkvt, bqkv, qkv, nullptr, nullptr, nullptr, nullptr, 4096, 3072, 1024, 12, 1024);
    vtrans_kernel<<<dim3(64, 32, 2), blk, 0, stream>>>(qkv, vT);
    attn_kernel<<<dim3(32, 32), dim3(512), 0, stream>>>(qkv, vT, mask, ctx);
    gemm256_bt<2, 0><<<dim3(64, 4), dim3(512), 0, stream>>>(
        ctx, wot, nullptr, nullptr, pw0, pw1, pw2, x1, 4096, 1024, 1024, 4, 256);
    addbias3b_ln_kernel<<<dim3(4096), blk, 0, stream>>>(x1, pw0, pw1, pw2, bo, x, ln2a, ln2b, xn2);

    // FFN1 (256^2 8-wave, relu) -> FFN2 (256^2 8-wave, split-K=4) + reduce(+b2+x1)
    gemm256_bt<0, 1><<<dim3(256, 1), dim3(512), 0, stream>>>(
        xn2, w1t, b1, ff1, nullptr, nullptr, nullptr, nullptr, 4096, 4096, 1024, 16, 1024);
    gemm256_bt<2, 0><<<dim3(64, 4), dim3(512), 0, stream>>>(
        ff1, w2t, nullptr, nullptr, pb0, pb1, pb2, out, 4096, 1024, 4096, 4, 1024);
    addbias3b_kernel<<<dim3(4096), blk, 0, stream>>>(out, pb0, pb1, pb2, b2, x1);
}

// Round 15
// 257.187 us; speedup vs baseline: 1.0404x; 1.0227x over previous
//
#include <hip/hip_runtime.h>
#include <hip/hip_bf16.h>

typedef __attribute__((ext_vector_type(8))) short short8;
typedef __attribute__((ext_vector_type(4))) float f32x4;
typedef __attribute__((ext_vector_type(4))) unsigned int u32x4;
using u16 = unsigned short;
typedef unsigned int u32;

__device__ __forceinline__ u16 f2bf(float f) {
    u32 u = __builtin_bit_cast(u32, f);
    u32 r = u + 0x7FFFu + ((u >> 16) & 1u);
    return (u16)(r >> 16);
}

__device__ __forceinline__ float bf2f(u32 w) {  // low 16 bits = bf16
    return __builtin_bit_cast(float, w << 16);
}
__device__ __forceinline__ float bf2f_hi(u32 w) {
    return __builtin_bit_cast(float, w & 0xFFFF0000u);
}

__device__ __forceinline__ float exp2fast(float x) {
    return __builtin_amdgcn_exp2f(x);  // v_exp_f32
}

__device__ __forceinline__ u32 cvtpk(float lo, float hi) {
    u32 r;
    asm("v_cvt_pk_bf16_f32 %0, %1, %2" : "=v"(r) : "v"(lo), "v"(hi));
    return r;
}

__device__ __forceinline__ void async_load16(const void* g, void* l) {
    __builtin_amdgcn_global_load_lds(
        (const __attribute__((address_space(1))) void*)g,
        (__attribute__((address_space(3))) void*)l, 16, 0, 0);
}

__device__ __forceinline__ void wg_barrier() {
    asm volatile("" ::: "memory");
    __builtin_amdgcn_s_barrier();
    asm volatile("" ::: "memory");
}

// ---------------- transpose body: w[K][N] tile -> wt[N][K], 32x32 ----------------
__device__ __forceinline__ void convt_body(const float* __restrict__ w,
                                           u16* __restrict__ wt, int K, int N,
                                           int bn, int bk) {
    __shared__ float tile[32][33];
    int tx = threadIdx.x & 31, ty = threadIdx.x >> 5;
#pragma unroll
    for (int i = 0; i < 4; i++)
        tile[ty + i * 8][tx] = w[(size_t)(bk + ty + i * 8) * N + bn + tx];
    __syncthreads();
#pragma unroll
    for (int i = 0; i < 4; i++)
        wt[(size_t)(bn + ty + i * 8) * K + bk + tx] = f2bf(tile[tx][ty + i * 8]);
}

// ---------------- fused prep: all 6 weight transposes + bias concat, one launch ----------------
// blocks [0,4096): squares wq/wk/wv/wo; [4096,8192): w1; [8192,12288): w2; [12288,12300): bias.
__global__ __launch_bounds__(256) void prep_kernel(const float* __restrict__ wq,
                                                   const float* __restrict__ wk,
                                                   const float* __restrict__ wv,
                                                   const float* __restrict__ wo,
                                                   const float* __restrict__ w1,
                                                   const float* __restrict__ w2,
                                                   u16* __restrict__ wqkvt,
                                                   u16* __restrict__ wot,
                                                   u16* __restrict__ w1t,
                                                   u16* __restrict__ w2t,
                                                   const float* __restrict__ bq,
                                                   const float* __restrict__ bk,
                                                   const float* __restrict__ bv,
                                                   float* __restrict__ bqkv) {
    int bid = blockIdx.x;
    if (bid < 4096) {
        int z = bid >> 10, idx = bid & 1023;
        const float* w = (z == 0) ? wq : (z == 1) ? wk : (z == 2) ? wv : wo;
        u16* wt = (z == 0) ? wqkvt : (z == 1) ? wqkvt + 1024 * 1024
                 : (z == 2) ? wqkvt + 2048 * 1024 : wot;
        convt_body(w, wt, 1024, 1024, (idx & 31) * 32, (idx >> 5) * 32);
    } else if (bid < 8192) {
        int idx = bid - 4096;  // w1: K=1024, N=4096; grid (128 bn, 32 bk)
        convt_body(w1, w1t, 1024, 4096, (idx & 127) * 32, (idx >> 7) * 32);
    } else if (bid < 12288) {
        int idx = bid - 8192;  // w2: K=4096, N=1024; grid (32 bn, 128 bk)
        convt_body(w2, w2t, 4096, 1024, (idx & 31) * 32, (idx >> 5) * 32);
    } else {
        int i = (bid - 12288) * 256 + threadIdx.x;  // 3072 total
        float v = (i < 1024) ? bq[i] : ((i < 2048) ? bk[i - 1024] : bv[i - 2048]);
        bqkv[i] = v;
    }
}

// ---------------- V transpose (bf16): qkv V-part [b][s][1024] -> vT[b*1024+col][2048] ----------------
__global__ __launch_bounds__(256) void vtrans_kernel(const u16* __restrict__ qkv,
                                                     u16* __restrict__ vT) {
    __shared__ u16 tile[32][33];
    int bs = blockIdx.x * 32;
    int bc = blockIdx.y * 32;
    int b  = blockIdx.z;
    int tx = threadIdx.x & 31, ty = threadIdx.x >> 5;
#pragma unroll
    for (int i = 0; i < 4; i++)
        tile[ty + i * 8][tx] = qkv[(size_t)(b * 2048 + bs + ty + i * 8) * 3072 + 2048 + bc + tx];
    __syncthreads();
#pragma unroll
    for (int i = 0; i < 4; i++)
        vT[(size_t)(b * 1024 + bc + ty + i * 8) * 2048 + bs + tx] = tile[tx][ty + i * 8];
}

// ---------------- LayerNorm (fp32 in, bf16 out) ----------------
__global__ __launch_bounds__(256) void ln_kernel(const float* __restrict__ x,
                                                 const float* __restrict__ ga,
                                                 const float* __restrict__ gb,
                                                 u16* __restrict__ out) {
    int row = blockIdx.x;
    const float4* xr = (const float4*)(x + (size_t)row * 1024);
    float4 v = xr[threadIdx.x];
    float s  = v.x + v.y + v.z + v.w;
    float s2 = v.x * v.x + v.y * v.y + v.z * v.z + v.w * v.w;
#pragma unroll
    for (int off = 32; off; off >>= 1) {
        s  += __shfl_down(s, off);
        s2 += __shfl_down(s2, off);
    }
    __shared__ float rs[4], rs2[4];
    int wid = threadIdx.x >> 6, lane = threadIdx.x & 63;
    if (lane == 0) { rs[wid] = s; rs2[wid] = s2; }
    __syncthreads();
    float S  = rs[0] + rs[1] + rs[2] + rs[3];
    float S2 = rs2[0] + rs2[1] + rs2[2] + rs2[3];
    float mean = S * (1.0f / 1024.0f);
    float var  = fmaxf((S2 - 1024.0f * mean * mean) * (1.0f / 1023.0f), 0.0f);
    float scale = ga[0] / (sqrtf(var) + 1e-6f);
    float shift = gb[0] - mean * scale;
    uint2 pv;
    pv.x = (u32)f2bf(v.x * scale + shift) | ((u32)f2bf(v.y * scale + shift) << 16);
    pv.y = (u32)f2bf(v.z * scale + shift) | ((u32)f2bf(v.w * scale + shift) << 16);
    *(uint2*)(out + (size_t)row * 1024 + threadIdx.x * 4) = pv;
}

// ---- fused reduce (3 bf16 partials): dst = dst + p0 + p1 + p2 + bias + resid ----
__global__ __launch_bounds__(256) void addbias3b_kernel(float* __restrict__ dst,
                                                        const u16* __restrict__ p0,
                                                        const u16* __restrict__ p1,
                                                        const u16* __restrict__ p2,
                                                        const float* __restrict__ bias,
                                                        const float* __restrict__ resid) {
    int i4 = blockIdx.x * 256 + threadIdx.x;
    float4 d  = ((const float4*)dst)[i4];
    uint2 ua = ((const uint2*)p0)[i4];
    uint2 ub = ((const uint2*)p1)[i4];
    uint2 uc = ((const uint2*)p2)[i4];
    float4 rr = ((const float4*)resid)[i4];
    float4 bb = *(const float4*)(bias + ((i4 * 4) & 1023));
    d.x += bf2f(ua.x) + bf2f(ub.x) + bf2f(uc.x) + bb.x + rr.x;
    d.y += bf2f_hi(ua.x) + bf2f_hi(ub.x) + bf2f_hi(uc.x) + bb.y + rr.y;
    d.z += bf2f(ua.y) + bf2f(ub.y) + bf2f(uc.y) + bb.z + rr.z;
    d.w += bf2f_hi(ua.y) + bf2f_hi(ub.y) + bf2f_hi(uc.y) + bb.w + rr.w;
    ((float4*)dst)[i4] = d;
}

// ---- fused reduce (3 bf16 partials) + bias + resid + LayerNorm: x1, xn = LN(x1) bf16 ----
__global__ __launch_bounds__(256) void addbias3b_ln_kernel(float* __restrict__ dst,
                                                           const u16* __restrict__ p0,
                                                           const u16* __restrict__ p1,
                                                           const u16* __restrict__ p2,
                                                           const float* __restrict__ bias,
                                                           const float* __restrict__ resid,
                                                           const float* __restrict__ ga,
                                                           const float* __restrict__ gb,
                                                           u16* __restrict__ xn) {
    int row = blockIdx.x;
    int i4 = row * 256 + threadIdx.x;
    float4 d  = ((const float4*)dst)[i4];
    uint2 ua = ((const uint2*)p0)[i4];
    uint2 ub = ((const uint2*)p1)[i4];
    uint2 uc = ((const uint2*)p2)[i4];
    float4 rr = ((const float4*)resid)[i4];
    float4 bb = *(const float4*)(bias + threadIdx.x * 4);
    d.x += bf2f(ua.x) + bf2f(ub.x) + bf2f(uc.x) + bb.x + rr.x;
    d.y += bf2f_hi(ua.x) + bf2f_hi(ub.x) + bf2f_hi(uc.x) + bb.y + rr.y;
    d.z += bf2f(ua.y) + bf2f(ub.y) + bf2f(uc.y) + bb.z + rr.z;
    d.w += bf2f_hi(ua.y) + bf2f_hi(ub.y) + bf2f_hi(uc.y) + bb.w + rr.w;
    ((float4*)dst)[i4] = d;

    float s  = d.x + d.y + d.z + d.w;
    float s2 = d.x * d.x + d.y * d.y + d.z * d.z + d.w * d.w;
#pragma unroll
    for (int off = 32; off; off >>= 1) {
        s  += __shfl_down(s, off);
        s2 += __shfl_down(s2, off);
    }
    __shared__ float rs[4], rs2[4];
    int wid = threadIdx.x >> 6, lane = threadIdx.x & 63;
    if (lane == 0) { rs[wid] = s; rs2[wid] = s2; }
    __syncthreads();
    float S  = rs[0] + rs[1] + rs[2] + rs[3];
    float S2 = rs2[0] + rs2[1] + rs2[2] + rs2[3];
    float mean = S * (1.0f / 1024.0f);
    float var  = fmaxf((S2 - 1024.0f * mean * mean) * (1.0f / 1023.0f), 0.0f);
    float scale = ga[0] / (sqrtf(var) + 1e-6f);
    float shift = gb[0] - mean * scale;
    uint2 pv;
    pv.x = (u32)f2bf(d.x * scale + shift) | ((u32)f2bf(d.y * scale + shift) << 16);
    pv.y = (u32)f2bf(d.z * scale + shift) | ((u32)f2bf(d.w * scale + shift) << 16);
    *(uint2*)(xn + (size_t)row * 1024 + threadIdx.x * 4) = pv;
}

// ---------------- 256x256 8-wave GEMM, BK=64, 4-phase, swizzled LDS, counted vmcnt ----------------
// MODE 0: bf16 out + bias (+relu). MODE 2: split-K via blockIdx.y (kLen per split);
//   z < gridDim.y-1 -> bf16 partial to P[z]; z == gridDim.y-1 -> f32 partial to Cf.
template <int MODE, int RELU>
__global__ __launch_bounds__(512) void gemm256_bt(const u16* __restrict__ A,
                                                  const u16* __restrict__ Bt,
                                                  const float* __restrict__ bias,
                                                  u16* __restrict__ C,
                                                  u16* __restrict__ P0,
                                                  u16* __restrict__ P1,
                                                  u16* __restrict__ P2,
                                                  float* __restrict__ Cf,
                                                  int M, int N, int K, int tilesN, int kLen) {
    __shared__ u16 lds[2][2][16384];
    const int tid = threadIdx.x;
    const int lane = tid & 63, wid = tid >> 6;
    const int l15 = lane & 15, l4 = lane >> 4;
    const int wm = wid >> 2, wn = wid & 3;

    int nwg = gridDim.x;
    int bid = blockIdx.x;
    int swz = (bid & 7) * (nwg >> 3) + (bid >> 3);
    int ty = swz / tilesN, tx = swz % tilesN;
    const int kOff = blockIdx.y * kLen;

    const u16* Ag = A + (size_t)(ty * 256) * K;
    const u16* Bg = Bt + (size_t)(tx * 256) * K;

    auto stage_half = [&](int slot, int ab, int half, const u16* G, int k0) {
#pragma unroll
        for (int j = 0; j < 2; j++) {
            int off16 = half * 1024 + j * 512 + tid;
            int r = off16 >> 3;
            int gs = (off16 & 7) ^ (r & 7);
            const u16* src = G + (size_t)r * K + k0 + gs * 8;
            u16* dst = &lds[slot][ab][(size_t)(half * 1024 + j * 512 + (wid << 6)) * 8];
            async_load16(src, dst);
        }
    };

    f32x4 acc[8][4] = {};
    const int nT = kLen >> 6;

    stage_half(0, 0, 0, Ag, kOff);
    stage_half(0, 0, 1, Ag, kOff);
    stage_half(0, 1, 0, Bg, kOff);
    stage_half(0, 1, 1, Bg, kOff);
    __builtin_amdgcn_sched_barrier(0);

    for (int t = 0; t < nT; ++t) {
        const int cs = t & 1, ns = cs ^ 1;
        const int k1 = kOff + ((t + 1) << 6);
        const bool pf = (t + 1 < nT);
#pragma unroll
        for (int ph = 0; ph < 4; ++ph) {
            if (ph == 0 && pf) { stage_half(ns, 0, 0, Ag, k1); stage_half(ns, 0, 1, Ag, k1); }
            if (ph == 1 && pf) { stage_half(ns, 1, 0, Bg, k1); stage_half(ns, 1, 1, Bg, k1); }
            __builtin_amdgcn_sched_barrier(0);
            if (ph == 0) {
                if (pf) asm volatile("s_waitcnt vmcnt(4)" ::: "memory");
                else    asm volatile("s_waitcnt vmcnt(0)" ::: "memory");
            }
            wg_barrier();

            const int rh = ph >> 1, ch = ph & 1;
            const u16* la = &lds[cs][0][0];
            const u16* lb = &lds[cs][1][0];
            short8 af[4][2], bf[2][2];
#pragma unroll
            for (int m2 = 0; m2 < 4; m2++) {
                int ra = wm * 128 + rh * 64 + m2 * 16 + l15;
#pragma unroll
                for (int ks = 0; ks < 2; ks++) {
                    int sl = (l4 + ks * 4) ^ (ra & 7);
                    af[m2][ks] = *(const short8*)&la[ra * 64 + sl * 8];
                }
            }
#pragma unroll
            for (int n2 = 0; n2 < 2; n2++) {
                int rb = wn * 64 + ch * 32 + n2 * 16 + l15;
#pragma unroll
                for (int ks = 0; ks < 2; ks++) {
                    int sl = (l4 + ks * 4) ^ (rb & 7);
                    bf[n2][ks] = *(const short8*)&lb[rb * 64 + sl * 8];
                }
            }
            __builtin_amdgcn_s_setprio(1);
#pragma unroll
            for (int m2 = 0; m2 < 4; m2++)
#pragma unroll
                for (int n2 = 0; n2 < 2; n2++)
#pragma unroll
                    for (int ks = 0; ks < 2; ks++)
                        acc[rh * 4 + m2][ch * 2 + n2] = __builtin_amdgcn_mfma_f32_16x16x32_bf16(
                            af[m2][ks], bf[n2][ks], acc[rh * 4 + m2][ch * 2 + n2], 0, 0, 0);
            __builtin_amdgcn_s_setprio(0);
            wg_barrier();
        }
    }

    if (MODE == 0) {
#pragma unroll
        for (int mi = 0; mi < 8; mi++) {
            int row0 = ty * 256 + wm * 128 + (mi >> 2) * 64 + (mi & 3) * 16 + l4 * 4;
#pragma unroll
            for (int ni = 0; ni < 4; ni++) {
                int col = tx * 256 + wn * 64 + (ni >> 1) * 32 + (ni & 1) * 16 + l15;
                float bc = bias[col];
#pragma unroll
                for (int jj = 0; jj < 4; jj++) {
                    float v = acc[mi][ni][jj] + bc;
                    if (RELU) v = fmaxf(v, 0.0f);
                    C[(size_t)(row0 + jj) * N + col] = f2bf(v);
                }
            }
        }
    } else {
        int z = blockIdx.y;
        bool last = (z == gridDim.y - 1);
        u16* P = (z == 0) ? P0 : (z == 1) ? P1 : P2;
#pragma unroll
        for (int mi = 0; mi < 8; mi++) {
            int row0 = ty * 256 + wm * 128 + (mi >> 2) * 64 + (mi & 3) * 16 + l4 * 4;
#pragma unroll
            for (int ni = 0; ni < 4; ni++) {
                int col = tx * 256 + wn * 64 + (ni >> 1) * 32 + (ni & 1) * 16 + l15;
#pragma unroll
                for (int jj = 0; jj < 4; jj++) {
                    float v = acc[mi][ni][jj];
                    if (last) Cf[(size_t)(row0 + jj) * N + col] = v;
                    else      P[(size_t)(row0 + jj) * N + col] = f2bf(v);
                }
            }
        }
    }
}

// ---------------- flash attention v6 (measured best): 8-wave split-S, PT-LDS P relayout ----------------
__global__ __launch_bounds__(512) void attn_kernel(const u16* __restrict__ qkv,
                                                   const u16* __restrict__ vT,
                                                   const int* __restrict__ mask,
                                                   u16* __restrict__ ctx) {
    const int S = 2048;
    const float C = 0.180336880f;  // 0.125 * log2(e)
    int qt = blockIdx.x;
    int bh = blockIdx.y;
    int b = bh >> 4, h = bh & 15;
    int tid = threadIdx.x;
    int wid = tid >> 6, lane = tid & 63;
    int l15 = lane & 15, l4 = lane >> 4;
    int g = wid >> 2, qw = wid & 3;

    __shared__ u16 Ks[2][64][72];
    __shared__ u16 Vs[2][64][72];
    __shared__ u32 PT[8][16][38];
    __shared__ float mbuf[2][4][16], lbuf[2][4][16];
    __shared__ int mflag;

    if (tid == 0) mflag = 1;
    __syncthreads();
    {
        const int* mrow = mask + b * S;
        int ok = 1;
#pragma unroll
        for (int i = 0; i < 4; i++) ok &= (mrow[tid * 4 + i] != 0);
        if (!ok) mflag = 0;
    }

    int qrow0 = qt * 64 + qw * 16;
    const u16* qb = qkv + (size_t)(b * S + qrow0) * 3072 + h * 64;
    short8 qf0 = *(const short8*)(qb + (size_t)l15 * 3072 + l4 * 8);
    short8 qf1 = *(const short8*)(qb + (size_t)l15 * 3072 + 32 + l4 * 8);

    f32x4 o[4] = {};
    float m_i = -1e30f, lp = 0.0f;
    __syncthreads();
    const int allones = mflag;
    const int* mrow = mask + b * S;

    int tl = tid & 255;
    int srow = tl >> 3, c8 = (tl & 7) * 8;
    const int kt0 = g * 16;
    short8 kreg[2], vreg[2];
#pragma unroll
    for (int p = 0; p < 2; p++) {
        int r = p * 32 + srow;
        kreg[p] = *(const short8*)(qkv + (size_t)(b * S + kt0 * 64 + r) * 3072 + 1024 + h * 64 + c8);
        vreg[p] = *(const short8*)(vT + (size_t)(bh * 64 + r) * 2048 + kt0 * 64 + c8);
    }

    for (int it = 0; it < 16; ++it) {
        const int kt = kt0 + it;
        wg_barrier();
#pragma unroll
        for (int p = 0; p < 2; p++) {
            int r = p * 32 + srow;
            *(short8*)&Ks[g][r][c8] = kreg[p];
            *(short8*)&Vs[g][r][c8] = vreg[p];
        }
        if (it + 1 < 16) {
#pragma unroll
            for (int p = 0; p < 2; p++) {
                int r = p * 32 + srow;
                kreg[p] = *(const short8*)(qkv + (size_t)(b * S + (kt + 1) * 64 + r) * 3072 + 1024 + h * 64 + c8);
                vreg[p] = *(const short8*)(vT + (size_t)(bh * 64 + r) * 2048 + (kt + 1) * 64 + c8);
            }
        }
        asm volatile("s_waitcnt lgkmcnt(0)" ::: "memory");
        wg_barrier();

        float sc[4][4];
#pragma unroll
        for (int kc = 0; kc < 4; kc++) {
            short8 kf0 = *(const short8*)&Ks[g][kc * 16 + l15][l4 * 8];
            short8 kf1 = *(const short8*)&Ks[g][kc * 16 + l15][32 + l4 * 8];
            f32x4 a = {};
            a = __builtin_amdgcn_mfma_f32_16x16x32_bf16(kf0, qf0, a, 0, 0, 0);
            a = __builtin_amdgcn_mfma_f32_16x16x32_bf16(kf1, qf1, a, 0, 0, 0);
            if (allones) {
#pragma unroll
                for (int j = 0; j < 4; j++) sc[kc][j] = a[j];
            } else {
#pragma unroll
                for (int j = 0; j < 4; j++) {
                    int mk = mrow[kt * 64 + kc * 16 + l4 * 4 + j];
                    sc[kc][j] = mk ? a[j] : -1e9f;
                }
            }
        }

        float lm = sc[0][0];
#pragma unroll
        for (int kc = 0; kc < 4; kc++)
#pragma unroll
            for (int j = 0; j < 4; j++) lm = fmaxf(lm, sc[kc][j]);
        if (!__all(lm <= m_i + 64.0f)) {
            float t = lm;
            t = fmaxf(t, __shfl_xor(t, 16));
            t = fmaxf(t, __shfl_xor(t, 32));
            float newm = fmaxf(m_i, t);
            float r = exp2fast((m_i - newm) * C);
            lp *= r;
            float rr0 = __shfl(r, l4 * 4 + 0);
            float rr1 = __shfl(r, l4 * 4 + 1);
            float rr2 = __shfl(r, l4 * 4 + 2);
            float rr3 = __shfl(r, l4 * 4 + 3);
#pragma unroll
            for (int dc = 0; dc < 4; dc++) {
                o[dc][0] *= rr0; o[dc][1] *= rr1; o[dc][2] *= rr2; o[dc][3] *= rr3;
            }
            m_i = newm;
        }

        float nb = -m_i * C;
#pragma unroll
        for (int kc = 0; kc < 4; kc++) {
            float p0 = exp2fast(fmaf(sc[kc][0], C, nb));
            float p1 = exp2fast(fmaf(sc[kc][1], C, nb));
            float p2 = exp2fast(fmaf(sc[kc][2], C, nb));
            float p3 = exp2fast(fmaf(sc[kc][3], C, nb));
            lp += (p0 + p1) + (p2 + p3);
            uint2 w;
            w.x = cvtpk(p0, p1);
            w.y = cvtpk(p2, p3);
            *(uint2*)&PT[wid][l15][kc * 8 + l4 * 2] = w;
        }

        uint2 r01 = *(const uint2*)&PT[wid][l15][l4 * 4];
        uint2 r23 = *(const uint2*)&PT[wid][l15][l4 * 4 + 2];
        uint2 r45 = *(const uint2*)&PT[wid][l15][16 + l4 * 4];
        uint2 r67 = *(const uint2*)&PT[wid][l15][16 + l4 * 4 + 2];
        u32x4 w0 = {r01.x, r01.y, r23.x, r23.y};
        u32x4 w1 = {r45.x, r45.y, r67.x, r67.y};
        short8 pa0 = __builtin_bit_cast(short8, w0);
        short8 pa1 = __builtin_bit_cast(short8, w1);

#pragma unroll
        for (int dc = 0; dc < 4; dc++) {
            short8 vf0 = *(const short8*)&Vs[g][dc * 16 + l15][l4 * 8];
            short8 vf1 = *(const short8*)&Vs[g][dc * 16 + l15][32 + l4 * 8];
            o[dc] = __builtin_amdgcn_mfma_f32_16x16x32_bf16(pa0, vf0, o[dc], 0, 0, 0);
            o[dc] = __builtin_amdgcn_mfma_f32_16x16x32_bf16(pa1, vf1, o[dc], 0, 0, 0);
        }
    }

    // -------- combine the two groups --------
    float lt = lp;
    lt += __shfl_xor(lt, 16);
    lt += __shfl_xor(lt, 32);
    if (l4 == 0) { mbuf[g][qw][l15] = m_i; lbuf[g][qw][l15] = lt; }
    __syncthreads();
    float mo = mbuf[g ^ 1][qw][l15], lo = lbuf[g ^ 1][qw][l15];
    float M  = fmaxf(m_i, mo);
    float rs = exp2fast((m_i - M) * C);
    float ro = exp2fast((mo - M) * C);
    float inv = 1.0f / (rs * lt + ro * lo);
    float rs_j[4], iv_j[4];
#pragma unroll
    for (int j = 0; j < 4; j++) {
        rs_j[j] = __shfl(rs,  l4 * 4 + j);
        iv_j[j] = __shfl(inv, l4 * 4 + j);
    }

    float* obuf = (float*)&Ks[0][0][0];  // 16 KB overlay on dead Ks
#pragma unroll
    for (int c = 0; c < 2; c++) {
        int dce = (g ^ 1) * 2 + c;
#pragma unroll
        for (int j = 0; j < 4; j++)
            obuf[(((g * 4 + qw) * 16) + l4 * 4 + j) * 32 + c * 16 + l15] = o[dce][j] * rs_j[j];
    }
    __syncthreads();
#pragma unroll
    for (int c = 0; c < 2; c++) {
        int dco = g * 2 + c;
#pragma unroll
        for (int j = 0; j < 4; j++) {
            float peer = obuf[((((g ^ 1) * 4 + qw) * 16) + l4 * 4 + j) * 32 + c * 16 + l15];
            float val = (o[dco][j] * rs_j[j] + peer) * iv_j[j];
            int row = qrow0 + l4 * 4 + j;
            ctx[(size_t)(b * S + row) * 1024 + h * 64 + dco * 16 + l15] = f2bf(val);
        }
    }
}

// ---------------- launcher ----------------
extern "C" void kernel_launch(void* const* d_in, const int* in_sizes, int n_in,
                              void* d_out, int out_size, void* d_ws, size_t ws_size,
                              hipStream_t stream) {
    const float* x    = (const float*)d_in[0];
    const int*   mask = (const int*)d_in[1];
    const float* wq   = (const float*)d_in[2];
    const float* bq   = (const float*)d_in[3];
    const float* wk   = (const float*)d_in[4];
    const float* bk   = (const float*)d_in[5];
    const float* wv   = (const float*)d_in[6];
    const float* bv   = (const float*)d_in[7];
    const float* wo   = (const float*)d_in[8];
    const float* bo   = (const float*)d_in[9];
    const float* w1   = (const float*)d_in[10];
    const float* b1   = (const float*)d_in[11];
    const float* w2   = (const float*)d_in[12];
    const float* b2   = (const float*)d_in[13];
    const float* ln1a = (const float*)d_in[14];
    const float* ln1b = (const float*)d_in[15];
    const float* ln2a = (const float*)d_in[16];
    const float* ln2b = (const float*)d_in[17];
    float* out = (float*)d_out;

    char* ws = (char*)d_ws;
    u16*   wqkvt = (u16*)(ws + 0);            //  6 MB (dead after QKV)
    u16*   wot   = (u16*)(ws + 6291456);      //  2 MB (dead after WO)
    u16*   w1t   = (u16*)(ws + 8388608);      //  8 MB (dead after FFN1)
    u16*   w2t   = (u16*)(ws + 16777216);     //  8 MB (live through FFN2)
    float* bqkv  = (float*)(ws + 25165824);   // 12 KB
    char*  regA  = ws + 26214400;
    u16*   xn1   = (u16*)(regA + 0);          //  8 MB
    u16*   vT    = (u16*)(regA + 0);          //  8 MB (aliases xn1; dead after attn)
    u16*   qkv   = (u16*)(regA + 8388608);    // 24 MB (dead after attn)
    u16*   ctx   = (u16*)(regA + 33554432);   //  8 MB (dead after WO)
    // WO bf16 partials (over dead qkv region):
    u16*   pw0   = (u16*)(regA + 8388608);    //  8 MB
    u16*   pw1   = (u16*)(regA + 16777216);   //  8 MB
    u16*   pw2   = (u16*)(regA + 25165824);   //  8 MB
    float* x1    = (float*)(ws + 68157440);   // 16 MB
    u16*   xn2   = (u16*)(regA + 0);          //  8 MB (vT dead; WO partials dead after reduce)
    u16*   ff1   = (u16*)(regA + 8388608);    // 32 MB (pw* + ctx dead by FFN1 time)
    // FFN2 bf16 partials (dead regions by FFN2 time):
    u16*   pb0   = (u16*)(ws + 0);            //  8 MB (over wqkvt+wot)
    u16*   pb1   = (u16*)(ws + 8388608);      //  8 MB (over w1t)
    u16*   pb2   = (u16*)(regA + 0);          //  8 MB (over xn2, dead after FFN1)

    dim3 blk(256);

    // all weight transposes + bias concat in ONE launch
    prep_kernel<<<dim3(12300), blk, 0, stream>>>(wq, wk, wv, wo, w1, w2,
                                                 wqkvt, wot, w1t, w2t, bq, bk, bv, bqkv);

    // LN1 -> QKV (256^2 8-wave) -> attn -> WO (256^2 split-K=4) + fused reduce+bo+x+LN2
    ln_kernel<<<dim3(4096), blk, 0, stream>>>(x, ln1a, ln1b, xn1);
    gemm256_bt<0, 0><<<dim3(192, 1), dim3(512), 0, stream>>>(
        xn1, wqkvt, bqkv, qkv, nullptr, nullptr, nullptr, nullptr, 4096, 3072, 1024, 12, 1024);
    vtrans_kernel<<<dim3(64, 32, 2), blk, 0, stream>>>(qkv, vT);
    attn_kernel<<<dim3(32, 32), dim3(512), 0, stream>>>(qkv, vT, mask, ctx);
    gemm256_bt<2, 0><<<dim3(64, 4), dim3(512), 0, stream>>>(
        ctx, wot, nullptr, nullptr, pw0, pw1, pw2, x1, 4096, 1024, 1024, 4, 256);
    addbias3b_ln_kernel<<<dim3(4096), blk, 0, stream>>>(x1, pw0, pw1, pw2, bo, x, ln2a, ln2b, xn2);

    // FFN1 (256^2 8-wave, relu) -> FFN2 (256^2 8-wave, split-K=4) + reduce(+b2+x1)
    gemm256_bt<0, 1><<<dim3(256, 1), dim3(512), 0, stream>>>(
        xn2, w1t, b1, ff1, nullptr, nullptr, nullptr, nullptr, 4096, 4096, 1024, 16, 1024);
    gemm256_bt<2, 0><<<dim3(64, 4), dim3(512), 0, stream>>>(
        ff1, w2t, nullptr, nullptr, pb0, pb1, pb2, out, 4096, 1024, 4096, 4, 1024);
    addbias3b_kernel<<<dim3(4096), blk, 0, stream>>>(out, pb0, pb1, pb2, b2, x1);
}

// Round 16
// 254.926 us; speedup vs baseline: 1.0496x; 1.0089x over previous
//
#include <hip/hip_runtime.h>
#include <hip/hip_bf16.h>

typedef __attribute__((ext_vector_type(8))) short short8;
typedef __attribute__((ext_vector_type(4))) float f32x4;
typedef __attribute__((ext_vector_type(4))) unsigned int u32x4;
using u16 = unsigned short;
typedef unsigned int u32;

__device__ __forceinline__ u16 f2bf(float f) {
    u32 u = __builtin_bit_cast(u32, f);
    u32 r = u + 0x7FFFu + ((u >> 16) & 1u);
    return (u16)(r >> 16);
}

__device__ __forceinline__ float bf2f(u32 w) {  // low 16 bits = bf16
    return __builtin_bit_cast(float, w << 16);
}
__device__ __forceinline__ float bf2f_hi(u32 w) {
    return __builtin_bit_cast(float, w & 0xFFFF0000u);
}

__device__ __forceinline__ float exp2fast(float x) {
    return __builtin_amdgcn_exp2f(x);  // v_exp_f32
}

__device__ __forceinline__ u32 cvtpk(float lo, float hi) {
    u32 r;
    asm("v_cvt_pk_bf16_f32 %0, %1, %2" : "=v"(r) : "v"(lo), "v"(hi));
    return r;
}

__device__ __forceinline__ void async_load16(const void* g, void* l) {
    __builtin_amdgcn_global_load_lds(
        (const __attribute__((address_space(1))) void*)g,
        (__attribute__((address_space(3))) void*)l, 16, 0, 0);
}

__device__ __forceinline__ void wg_barrier() {
    asm volatile("" ::: "memory");
    __builtin_amdgcn_s_barrier();
    asm volatile("" ::: "memory");
}

// ---------------- transpose body: w[K][N] tile -> wt[N][K], 32x32 ----------------
__device__ __forceinline__ void convt_body(const float* __restrict__ w,
                                           u16* __restrict__ wt, int K, int N,
                                           int bn, int bk) {
    __shared__ float tile[32][33];
    int tx = threadIdx.x & 31, ty = threadIdx.x >> 5;
#pragma unroll
    for (int i = 0; i < 4; i++)
        tile[ty + i * 8][tx] = w[(size_t)(bk + ty + i * 8) * N + bn + tx];
    __syncthreads();
#pragma unroll
    for (int i = 0; i < 4; i++)
        wt[(size_t)(bn + ty + i * 8) * K + bk + tx] = f2bf(tile[tx][ty + i * 8]);
}

// ---------------- LayerNorm row body (fp32 in, bf16 out) ----------------
__device__ __forceinline__ void ln_body(const float* __restrict__ x,
                                        const float* __restrict__ ga,
                                        const float* __restrict__ gb,
                                        u16* __restrict__ out, int row) {
    const float4* xr = (const float4*)(x + (size_t)row * 1024);
    float4 v = xr[threadIdx.x];
    float s  = v.x + v.y + v.z + v.w;
    float s2 = v.x * v.x + v.y * v.y + v.z * v.z + v.w * v.w;
#pragma unroll
    for (int off = 32; off; off >>= 1) {
        s  += __shfl_down(s, off);
        s2 += __shfl_down(s2, off);
    }
    __shared__ float rs[4], rs2[4];
    int wid = threadIdx.x >> 6, lane = threadIdx.x & 63;
    if (lane == 0) { rs[wid] = s; rs2[wid] = s2; }
    __syncthreads();
    float S  = rs[0] + rs[1] + rs[2] + rs[3];
    float S2 = rs2[0] + rs2[1] + rs2[2] + rs2[3];
    float mean = S * (1.0f / 1024.0f);
    float var  = fmaxf((S2 - 1024.0f * mean * mean) * (1.0f / 1023.0f), 0.0f);
    float scale = ga[0] / (sqrtf(var) + 1e-6f);
    float shift = gb[0] - mean * scale;
    uint2 pv;
    pv.x = (u32)f2bf(v.x * scale + shift) | ((u32)f2bf(v.y * scale + shift) << 16);
    pv.y = (u32)f2bf(v.z * scale + shift) | ((u32)f2bf(v.w * scale + shift) << 16);
    *(uint2*)(out + (size_t)row * 1024 + threadIdx.x * 4) = pv;
}

// ---------------- fused prep: 6 weight transposes + bias concat + LN1, one launch ----------------
// blocks [0,4096): squares wq/wk/wv/wo; [4096,8192): w1; [8192,12288): w2;
// [12288,12300): bias concat; [12300,16396): LN1 rows.
__global__ __launch_bounds__(256) void prep_kernel(const float* __restrict__ wq,
                                                   const float* __restrict__ wk,
                                                   const float* __restrict__ wv,
                                                   const float* __restrict__ wo,
                                                   const float* __restrict__ w1,
                                                   const float* __restrict__ w2,
                                                   u16* __restrict__ wqkvt,
                                                   u16* __restrict__ wot,
                                                   u16* __restrict__ w1t,
                                                   u16* __restrict__ w2t,
                                                   const float* __restrict__ bq,
                                                   const float* __restrict__ bk,
                                                   const float* __restrict__ bv,
                                                   float* __restrict__ bqkv,
                                                   const float* __restrict__ x,
                                                   const float* __restrict__ ln1a,
                                                   const float* __restrict__ ln1b,
                                                   u16* __restrict__ xn1) {
    int bid = blockIdx.x;
    if (bid < 4096) {
        int z = bid >> 10, idx = bid & 1023;
        const float* w = (z == 0) ? wq : (z == 1) ? wk : (z == 2) ? wv : wo;
        u16* wt = (z == 0) ? wqkvt : (z == 1) ? wqkvt + 1024 * 1024
                 : (z == 2) ? wqkvt + 2048 * 1024 : wot;
        convt_body(w, wt, 1024, 1024, (idx & 31) * 32, (idx >> 5) * 32);
    } else if (bid < 8192) {
        int idx = bid - 4096;  // w1: K=1024, N=4096
        convt_body(w1, w1t, 1024, 4096, (idx & 127) * 32, (idx >> 7) * 32);
    } else if (bid < 12288) {
        int idx = bid - 8192;  // w2: K=4096, N=1024
        convt_body(w2, w2t, 4096, 1024, (idx & 31) * 32, (idx >> 5) * 32);
    } else if (bid < 12300) {
        int i = (bid - 12288) * 256 + threadIdx.x;  // 3072 total
        float v = (i < 1024) ? bq[i] : ((i < 2048) ? bk[i - 1024] : bv[i - 2048]);
        bqkv[i] = v;
    } else {
        ln_body(x, ln1a, ln1b, xn1, bid - 12300);  // 4096 rows
    }
}

// ---------------- V transpose (bf16): qkv V-part [b][s][1024] -> vT[b*1024+col][2048] ----------------
__global__ __launch_bounds__(256) void vtrans_kernel(const u16* __restrict__ qkv,
                                                     u16* __restrict__ vT) {
    __shared__ u16 tile[32][33];
    int bs = blockIdx.x * 32;
    int bc = blockIdx.y * 32;
    int b  = blockIdx.z;
    int tx = threadIdx.x & 31, ty = threadIdx.x >> 5;
#pragma unroll
    for (int i = 0; i < 4; i++)
        tile[ty + i * 8][tx] = qkv[(size_t)(b * 2048 + bs + ty + i * 8) * 3072 + 2048 + bc + tx];
    __syncthreads();
#pragma unroll
    for (int i = 0; i < 4; i++)
        vT[(size_t)(b * 1024 + bc + ty + i * 8) * 2048 + bs + tx] = tile[tx][ty + i * 8];
}

// ---- fused reduce (3 bf16 partials): dst = dst + p0 + p1 + p2 + bias + resid ----
__global__ __launch_bounds__(256) void addbias3b_kernel(float* __restrict__ dst,
                                                        const u16* __restrict__ p0,
                                                        const u16* __restrict__ p1,
                                                        const u16* __restrict__ p2,
                                                        const float* __restrict__ bias,
                                                        const float* __restrict__ resid) {
    int i4 = blockIdx.x * 256 + threadIdx.x;
    float4 d  = ((const float4*)dst)[i4];
    uint2 ua = ((const uint2*)p0)[i4];
    uint2 ub = ((const uint2*)p1)[i4];
    uint2 uc = ((const uint2*)p2)[i4];
    float4 rr = ((const float4*)resid)[i4];
    float4 bb = *(const float4*)(bias + ((i4 * 4) & 1023));
    d.x += bf2f(ua.x) + bf2f(ub.x) + bf2f(uc.x) + bb.x + rr.x;
    d.y += bf2f_hi(ua.x) + bf2f_hi(ub.x) + bf2f_hi(uc.x) + bb.y + rr.y;
    d.z += bf2f(ua.y) + bf2f(ub.y) + bf2f(uc.y) + bb.z + rr.z;
    d.w += bf2f_hi(ua.y) + bf2f_hi(ub.y) + bf2f_hi(uc.y) + bb.w + rr.w;
    ((float4*)dst)[i4] = d;
}

// ---- fused reduce (3 bf16 partials) + bias + resid + LayerNorm: x1, xn = LN(x1) bf16 ----
__global__ __launch_bounds__(256) void addbias3b_ln_kernel(float* __restrict__ dst,
                                                           const u16* __restrict__ p0,
                                                           const u16* __restrict__ p1,
                                                           const u16* __restrict__ p2,
                                                           const float* __restrict__ bias,
                                                           const float* __restrict__ resid,
                                                           const float* __restrict__ ga,
                                                           const float* __restrict__ gb,
                                                           u16* __restrict__ xn) {
    int row = blockIdx.x;
    int i4 = row * 256 + threadIdx.x;
    float4 d  = ((const float4*)dst)[i4];
    uint2 ua = ((const uint2*)p0)[i4];
    uint2 ub = ((const uint2*)p1)[i4];
    uint2 uc = ((const uint2*)p2)[i4];
    float4 rr = ((const float4*)resid)[i4];
    float4 bb = *(const float4*)(bias + threadIdx.x * 4);
    d.x += bf2f(ua.x) + bf2f(ub.x) + bf2f(uc.x) + bb.x + rr.x;
    d.y += bf2f_hi(ua.x) + bf2f_hi(ub.x) + bf2f_hi(uc.x) + bb.y + rr.y;
    d.z += bf2f(ua.y) + bf2f(ub.y) + bf2f(uc.y) + bb.z + rr.z;
    d.w += bf2f_hi(ua.y) + bf2f_hi(ub.y) + bf2f_hi(uc.y) + bb.w + rr.w;
    ((float4*)dst)[i4] = d;

    float s  = d.x + d.y + d.z + d.w;
    float s2 = d.x * d.x + d.y * d.y + d.z * d.z + d.w * d.w;
#pragma unroll
    for (int off = 32; off; off >>= 1) {
        s  += __shfl_down(s, off);
        s2 += __shfl_down(s2, off);
    }
    __shared__ float rs[4], rs2[4];
    int wid = threadIdx.x >> 6, lane = threadIdx.x & 63;
    if (lane == 0) { rs[wid] = s; rs2[wid] = s2; }
    __syncthreads();
    float S  = rs[0] + rs[1] + rs[2] + rs[3];
    float S2 = rs2[0] + rs2[1] + rs2[2] + rs2[3];
    float mean = S * (1.0f / 1024.0f);
    float var  = fmaxf((S2 - 1024.0f * mean * mean) * (1.0f / 1023.0f), 0.0f);
    float scale = ga[0] / (sqrtf(var) + 1e-6f);
    float shift = gb[0] - mean * scale;
    uint2 pv;
    pv.x = (u32)f2bf(d.x * scale + shift) | ((u32)f2bf(d.y * scale + shift) << 16);
    pv.y = (u32)f2bf(d.z * scale + shift) | ((u32)f2bf(d.w * scale + shift) << 16);
    *(uint2*)(xn + (size_t)row * 1024 + threadIdx.x * 4) = pv;
}

// ---------------- 256x256 8-wave GEMM, BK=64, 4-phase, swizzled LDS, counted vmcnt ----------------
// MODE 0: bf16 out + bias (+relu). MODE 2: split-K via blockIdx.y (kLen per split);
//   z < gridDim.y-1 -> bf16 partial to P[z]; z == gridDim.y-1 -> f32 partial to Cf.
template <int MODE, int RELU>
__global__ __launch_bounds__(512) void gemm256_bt(const u16* __restrict__ A,
                                                  const u16* __restrict__ Bt,
                                                  const float* __restrict__ bias,
                                                  u16* __restrict__ C,
                                                  u16* __restrict__ P0,
                                                  u16* __restrict__ P1,
                                                  u16* __restrict__ P2,
                                                  float* __restrict__ Cf,
                                                  int M, int N, int K, int tilesN, int kLen) {
    __shared__ u16 lds[2][2][16384];
    const int tid = threadIdx.x;
    const int lane = tid & 63, wid = tid >> 6;
    const int l15 = lane & 15, l4 = lane >> 4;
    const int wm = wid >> 2, wn = wid & 3;

    int nwg = gridDim.x;
    int bid = blockIdx.x;
    int swz = (bid & 7) * (nwg >> 3) + (bid >> 3);
    int ty = swz / tilesN, tx = swz % tilesN;
    const int kOff = blockIdx.y * kLen;

    const u16* Ag = A + (size_t)(ty * 256) * K;
    const u16* Bg = Bt + (size_t)(tx * 256) * K;

    auto stage_half = [&](int slot, int ab, int half, const u16* G, int k0) {
#pragma unroll
        for (int j = 0; j < 2; j++) {
            int off16 = half * 1024 + j * 512 + tid;
            int r = off16 >> 3;
            int gs = (off16 & 7) ^ (r & 7);
            const u16* src = G + (size_t)r * K + k0 + gs * 8;
            u16* dst = &lds[slot][ab][(size_t)(half * 1024 + j * 512 + (wid << 6)) * 8];
            async_load16(src, dst);
        }
    };

    f32x4 acc[8][4] = {};
    const int nT = kLen >> 6;

    stage_half(0, 0, 0, Ag, kOff);
    stage_half(0, 0, 1, Ag, kOff);
    stage_half(0, 1, 0, Bg, kOff);
    stage_half(0, 1, 1, Bg, kOff);
    __builtin_amdgcn_sched_barrier(0);

    for (int t = 0; t < nT; ++t) {
        const int cs = t & 1, ns = cs ^ 1;
        const int k1 = kOff + ((t + 1) << 6);
        const bool pf = (t + 1 < nT);
#pragma unroll
        for (int ph = 0; ph < 4; ++ph) {
            if (ph == 0 && pf) { stage_half(ns, 0, 0, Ag, k1); stage_half(ns, 0, 1, Ag, k1); }
            if (ph == 1 && pf) { stage_half(ns, 1, 0, Bg, k1); stage_half(ns, 1, 1, Bg, k1); }
            __builtin_amdgcn_sched_barrier(0);
            if (ph == 0) {
                if (pf) asm volatile("s_waitcnt vmcnt(4)" ::: "memory");
                else    asm volatile("s_waitcnt vmcnt(0)" ::: "memory");
            }
            wg_barrier();

            const int rh = ph >> 1, ch = ph & 1;
            const u16* la = &lds[cs][0][0];
            const u16* lb = &lds[cs][1][0];
            short8 af[4][2], bf[2][2];
#pragma unroll
            for (int m2 = 0; m2 < 4; m2++) {
                int ra = wm * 128 + rh * 64 + m2 * 16 + l15;
#pragma unroll
                for (int ks = 0; ks < 2; ks++) {
                    int sl = (l4 + ks * 4) ^ (ra & 7);
                    af[m2][ks] = *(const short8*)&la[ra * 64 + sl * 8];
                }
            }
#pragma unroll
            for (int n2 = 0; n2 < 2; n2++) {
                int rb = wn * 64 + ch * 32 + n2 * 16 + l15;
#pragma unroll
                for (int ks = 0; ks < 2; ks++) {
                    int sl = (l4 + ks * 4) ^ (rb & 7);
                    bf[n2][ks] = *(const short8*)&lb[rb * 64 + sl * 8];
                }
            }
            __builtin_amdgcn_s_setprio(1);
#pragma unroll
            for (int m2 = 0; m2 < 4; m2++)
#pragma unroll
                for (int n2 = 0; n2 < 2; n2++)
#pragma unroll
                    for (int ks = 0; ks < 2; ks++)
                        acc[rh * 4 + m2][ch * 2 + n2] = __builtin_amdgcn_mfma_f32_16x16x32_bf16(
                            af[m2][ks], bf[n2][ks], acc[rh * 4 + m2][ch * 2 + n2], 0, 0, 0);
            __builtin_amdgcn_s_setprio(0);
            wg_barrier();
        }
    }

    if (MODE == 0) {
#pragma unroll
        for (int mi = 0; mi < 8; mi++) {
            int row0 = ty * 256 + wm * 128 + (mi >> 2) * 64 + (mi & 3) * 16 + l4 * 4;
#pragma unroll
            for (int ni = 0; ni < 4; ni++) {
                int col = tx * 256 + wn * 64 + (ni >> 1) * 32 + (ni & 1) * 16 + l15;
                float bc = bias[col];
#pragma unroll
                for (int jj = 0; jj < 4; jj++) {
                    float v = acc[mi][ni][jj] + bc;
                    if (RELU) v = fmaxf(v, 0.0f);
                    C[(size_t)(row0 + jj) * N + col] = f2bf(v);
                }
            }
        }
    } else {
        int z = blockIdx.y;
        bool last = (z == gridDim.y - 1);
        u16* P = (z == 0) ? P0 : (z == 1) ? P1 : P2;
#pragma unroll
        for (int mi = 0; mi < 8; mi++) {
            int row0 = ty * 256 + wm * 128 + (mi >> 2) * 64 + (mi & 3) * 16 + l4 * 4;
#pragma unroll
            for (int ni = 0; ni < 4; ni++) {
                int col = tx * 256 + wn * 64 + (ni >> 1) * 32 + (ni & 1) * 16 + l15;
#pragma unroll
                for (int jj = 0; jj < 4; jj++) {
                    float v = acc[mi][ni][jj];
                    if (last) Cf[(size_t)(row0 + jj) * N + col] = v;
                    else      P[(size_t)(row0 + jj) * N + col] = f2bf(v);
                }
            }
        }
    }
}

// ---------------- flash attention v6 (measured best): 8-wave split-S, PT-LDS P relayout ----------------
__global__ __launch_bounds__(512) void attn_kernel(const u16* __restrict__ qkv,
                                                   const u16* __restrict__ vT,
                                                   const int* __restrict__ mask,
                                                   u16* __restrict__ ctx) {
    const int S = 2048;
    const float C = 0.180336880f;  // 0.125 * log2(e)
    int qt = blockIdx.x;
    int bh = blockIdx.y;
    int b = bh >> 4, h = bh & 15;
    int tid = threadIdx.x;
    int wid = tid >> 6, lane = tid & 63;
    int l15 = lane & 15, l4 = lane >> 4;
    int g = wid >> 2, qw = wid & 3;

    __shared__ u16 Ks[2][64][72];
    __shared__ u16 Vs[2][64][72];
    __shared__ u32 PT[8][16][38];
    __shared__ float mbuf[2][4][16], lbuf[2][4][16];
    __shared__ int mflag;

    if (tid == 0) mflag = 1;
    __syncthreads();
    {
        const int* mrow = mask + b * S;
        int ok = 1;
#pragma unroll
        for (int i = 0; i < 4; i++) ok &= (mrow[tid * 4 + i] != 0);
        if (!ok) mflag = 0;
    }

    int qrow0 = qt * 64 + qw * 16;
    const u16* qb = qkv + (size_t)(b * S + qrow0) * 3072 + h * 64;
    short8 qf0 = *(const short8*)(qb + (size_t)l15 * 3072 + l4 * 8);
    short8 qf1 = *(const short8*)(qb + (size_t)l15 * 3072 + 32 + l4 * 8);

    f32x4 o[4] = {};
    float m_i = -1e30f, lp = 0.0f;
    __syncthreads();
    const int allones = mflag;
    const int* mrow = mask + b * S;

    int tl = tid & 255;
    int srow = tl >> 3, c8 = (tl & 7) * 8;
    const int kt0 = g * 16;
    short8 kreg[2], vreg[2];
#pragma unroll
    for (int p = 0; p < 2; p++) {
        int r = p * 32 + srow;
        kreg[p] = *(const short8*)(qkv + (size_t)(b * S + kt0 * 64 + r) * 3072 + 1024 + h * 64 + c8);
        vreg[p] = *(const short8*)(vT + (size_t)(bh * 64 + r) * 2048 + kt0 * 64 + c8);
    }

    for (int it = 0; it < 16; ++it) {
        const int kt = kt0 + it;
        wg_barrier();
#pragma unroll
        for (int p = 0; p < 2; p++) {
            int r = p * 32 + srow;
            *(short8*)&Ks[g][r][c8] = kreg[p];
            *(short8*)&Vs[g][r][c8] = vreg[p];
        }
        if (it + 1 < 16) {
#pragma unroll
            for (int p = 0; p < 2; p++) {
                int r = p * 32 + srow;
                kreg[p] = *(const short8*)(qkv + (size_t)(b * S + (kt + 1) * 64 + r) * 3072 + 1024 + h * 64 + c8);
                vreg[p] = *(const short8*)(vT + (size_t)(bh * 64 + r) * 2048 + (kt + 1) * 64 + c8);
            }
        }
        asm volatile("s_waitcnt lgkmcnt(0)" ::: "memory");
        wg_barrier();

        float sc[4][4];
#pragma unroll
        for (int kc = 0; kc < 4; kc++) {
            short8 kf0 = *(const short8*)&Ks[g][kc * 16 + l15][l4 * 8];
            short8 kf1 = *(const short8*)&Ks[g][kc * 16 + l15][32 + l4 * 8];
            f32x4 a = {};
            a = __builtin_amdgcn_mfma_f32_16x16x32_bf16(kf0, qf0, a, 0, 0, 0);
            a = __builtin_amdgcn_mfma_f32_16x16x32_bf16(kf1, qf1, a, 0, 0, 0);
            if (allones) {
#pragma unroll
                for (int j = 0; j < 4; j++) sc[kc][j] = a[j];
            } else {
#pragma unroll
                for (int j = 0; j < 4; j++) {
                    int mk = mrow[kt * 64 + kc * 16 + l4 * 4 + j];
                    sc[kc][j] = mk ? a[j] : -1e9f;
                }
            }
        }

        float lm = sc[0][0];
#pragma unroll
        for (int kc = 0; kc < 4; kc++)
#pragma unroll
            for (int j = 0; j < 4; j++) lm = fmaxf(lm, sc[kc][j]);
        if (!__all(lm <= m_i + 64.0f)) {
            float t = lm;
            t = fmaxf(t, __shfl_xor(t, 16));
            t = fmaxf(t, __shfl_xor(t, 32));
            float newm = fmaxf(m_i, t);
            float r = exp2fast((m_i - newm) * C);
            lp *= r;
            float rr0 = __shfl(r, l4 * 4 + 0);
            float rr1 = __shfl(r, l4 * 4 + 1);
            float rr2 = __shfl(r, l4 * 4 + 2);
            float rr3 = __shfl(r, l4 * 4 + 3);
#pragma unroll
            for (int dc = 0; dc < 4; dc++) {
                o[dc][0] *= rr0; o[dc][1] *= rr1; o[dc][2] *= rr2; o[dc][3] *= rr3;
            }
            m_i = newm;
        }

        float nb = -m_i * C;
#pragma unroll
        for (int kc = 0; kc < 4; kc++) {
            float p0 = exp2fast(fmaf(sc[kc][0], C, nb));
            float p1 = exp2fast(fmaf(sc[kc][1], C, nb));
            float p2 = exp2fast(fmaf(sc[kc][2], C, nb));
            float p3 = exp2fast(fmaf(sc[kc][3], C, nb));
            lp += (p0 + p1) + (p2 + p3);
            uint2 w;
            w.x = cvtpk(p0, p1);
            w.y = cvtpk(p2, p3);
            *(uint2*)&PT[wid][l15][kc * 8 + l4 * 2] = w;
        }

        uint2 r01 = *(const uint2*)&PT[wid][l15][l4 * 4];
        uint2 r23 = *(const uint2*)&PT[wid][l15][l4 * 4 + 2];
        uint2 r45 = *(const uint2*)&PT[wid][l15][16 + l4 * 4];
        uint2 r67 = *(const uint2*)&PT[wid][l15][16 + l4 * 4 + 2];
        u32x4 w0 = {r01.x, r01.y, r23.x, r23.y};
        u32x4 w1 = {r45.x, r45.y, r67.x, r67.y};
        short8 pa0 = __builtin_bit_cast(short8, w0);
        short8 pa1 = __builtin_bit_cast(short8, w1);

#pragma unroll
        for (int dc = 0; dc < 4; dc++) {
            short8 vf0 = *(const short8*)&Vs[g][dc * 16 + l15][l4 * 8];
            short8 vf1 = *(const short8*)&Vs[g][dc * 16 + l15][32 + l4 * 8];
            o[dc] = __builtin_amdgcn_mfma_f32_16x16x32_bf16(pa0, vf0, o[dc], 0, 0, 0);
            o[dc] = __builtin_amdgcn_mfma_f32_16x16x32_bf16(pa1, vf1, o[dc], 0, 0, 0);
        }
    }

    // -------- combine the two groups --------
    float lt = lp;
    lt += __shfl_xor(lt, 16);
    lt += __shfl_xor(lt, 32);
    if (l4 == 0) { mbuf[g][qw][l15] = m_i; lbuf[g][qw][l15] = lt; }
    __syncthreads();
    float mo = mbuf[g ^ 1][qw][l15], lo = lbuf[g ^ 1][qw][l15];
    float M  = fmaxf(m_i, mo);
    float rs = exp2fast((m_i - M) * C);
    float ro = exp2fast((mo - M) * C);
    float inv = 1.0f / (rs * lt + ro * lo);
    float rs_j[4], iv_j[4];
#pragma unroll
    for (int j = 0; j < 4; j++) {
        rs_j[j] = __shfl(rs,  l4 * 4 + j);
        iv_j[j] = __shfl(inv, l4 * 4 + j);
    }

    float* obuf = (float*)&Ks[0][0][0];  // 16 KB overlay on dead Ks
#pragma unroll
    for (int c = 0; c < 2; c++) {
        int dce = (g ^ 1) * 2 + c;
#pragma unroll
        for (int j = 0; j < 4; j++)
            obuf[(((g * 4 + qw) * 16) + l4 * 4 + j) * 32 + c * 16 + l15] = o[dce][j] * rs_j[j];
    }
    __syncthreads();
#pragma unroll
    for (int c = 0; c < 2; c++) {
        int dco = g * 2 + c;
#pragma unroll
        for (int j = 0; j < 4; j++) {
            float peer = obuf[((((g ^ 1) * 4 + qw) * 16) + l4 * 4 + j) * 32 + c * 16 + l15];
            float val = (o[dco][j] * rs_j[j] + peer) * iv_j[j];
            int row = qrow0 + l4 * 4 + j;
            ctx[(size_t)(b * S + row) * 1024 + h * 64 + dco * 16 + l15] = f2bf(val);
        }
    }
}

// ---------------- launcher ----------------
extern "C" void kernel_launch(void* const* d_in, const int* in_sizes, int n_in,
                              void* d_out, int out_size, void* d_ws, size_t ws_size,
                              hipStream_t stream) {
    const float* x    = (const float*)d_in[0];
    const int*   mask = (const int*)d_in[1];
    const float* wq   = (const float*)d_in[2];
    const float* bq   = (const float*)d_in[3];
    const float* wk   = (const float*)d_in[4];
    const float* bk   = (const float*)d_in[5];
    const float* wv   = (const float*)d_in[6];
    const float* bv   = (const float*)d_in[7];
    const float* wo   = (const float*)d_in[8];
    const float* bo   = (const float*)d_in[9];
    const float* w1   = (const float*)d_in[10];
    const float* b1   = (const float*)d_in[11];
    const float* w2   = (const float*)d_in[12];
    const float* b2   = (const float*)d_in[13];
    const float* ln1a = (const float*)d_in[14];
    const float* ln1b = (const float*)d_in[15];
    const float* ln2a = (const float*)d_in[16];
    const float* ln2b = (const float*)d_in[17];
    float* out = (float*)d_out;

    char* ws = (char*)d_ws;
    u16*   wqkvt = (u16*)(ws + 0);            //  6 MB (dead after QKV)
    u16*   wot   = (u16*)(ws + 6291456);      //  2 MB (dead after WO)
    u16*   w1t   = (u16*)(ws + 8388608);      //  8 MB (dead after FFN1)
    u16*   w2t   = (u16*)(ws + 16777216);     //  8 MB (live through FFN2)
    float* bqkv  = (float*)(ws + 25165824);   // 12 KB
    char*  regA  = ws + 26214400;
    u16*   xn1   = (u16*)(regA + 0);          //  8 MB
    u16*   vT    = (u16*)(regA + 0);          //  8 MB (aliases xn1; dead after attn)
    u16*   qkv   = (u16*)(regA + 8388608);    // 24 MB (dead after attn)
    u16*   ctx   = (u16*)(regA + 33554432);   //  8 MB (dead after WO)
    // WO bf16 partials (over dead qkv region):
    u16*   pw0   = (u16*)(regA + 8388608);    //  8 MB
    u16*   pw1   = (u16*)(regA + 16777216);   //  8 MB
    u16*   pw2   = (u16*)(regA + 25165824);   //  8 MB
    float* x1    = (float*)(ws + 68157440);   // 16 MB
    u16*   xn2   = (u16*)(regA + 0);          //  8 MB (vT dead; WO partials dead after reduce)
    u16*   ff1   = (u16*)(regA + 8388608);    // 32 MB (pw* + ctx dead by FFN1 time)
    // FFN2 bf16 partials (dead regions by FFN2 time):
    u16*   pb0   = (u16*)(ws + 0);            //  8 MB (over wqkvt+wot)
    u16*   pb1   = (u16*)(ws + 8388608);      //  8 MB (over w1t)
    u16*   pb2   = (u16*)(regA + 0);          //  8 MB (over xn2, dead after FFN1)

    dim3 blk(256);

    // all weight transposes + bias concat + LN1 in ONE launch
    prep_kernel<<<dim3(16396), blk, 0, stream>>>(wq, wk, wv, wo, w1, w2,
                                                 wqkvt, wot, w1t, w2t, bq, bk, bv, bqkv,
                                                 x, ln1a, ln1b, xn1);

    // QKV (256^2 8-wave) -> attn -> WO (256^2 split-K=4) + fused reduce+bo+x+LN2
    gemm256_bt<0, 0><<<dim3(192, 1), dim3(512), 0, stream>>>(
        xn1, wqkvt, bqkv, qkv, nullptr, nullptr, nullptr, nullptr, 4096, 3072, 1024, 12, 1024);
    vtrans_kernel<<<dim3(64, 32, 2), blk, 0, stream>>>(qkv, vT);
    attn_kernel<<<dim3(32, 32), dim3(512), 0, stream>>>(qkv, vT, mask, ctx);
    gemm256_bt<2, 0><<<dim3(64, 4), dim3(512), 0, stream>>>(
        ctx, wot, nullptr, nullptr, pw0, pw1, pw2, x1, 4096, 1024, 1024, 4, 256);
    addbias3b_ln_kernel<<<dim3(4096), blk, 0, stream>>>(x1, pw0, pw1, pw2, bo, x, ln2a, ln2b, xn2);

    // FFN1 (256^2 8-wave, relu) -> FFN2 (256^2 8-wave, split-K=4) + reduce(+b2+x1)
    gemm256_bt<0, 1><<<dim3(256, 1), dim3(512), 0, stream>>>(
        xn2, w1t, b1, ff1, nullptr, nullptr, nullptr, nullptr, 4096, 4096, 1024, 16, 1024);
    gemm256_bt<2, 0><<<dim3(64, 4), dim3(512), 0, stream>>>(
        ff1, w2t, nullptr, nullptr, pb0, pb1, pb2, out, 4096, 1024, 4096, 4, 1024);
    addbias3b_kernel<<<dim3(4096), blk, 0, stream>>>(out, pb0, pb1, pb2, b2, x1);
}

// Round 17
// 252.813 us; speedup vs baseline: 1.0584x; 1.0084x over previous
//
#include <hip/hip_runtime.h>
#include <hip/hip_bf16.h>

typedef __attribute__((ext_vector_type(8))) short short8;
typedef __attribute__((ext_vector_type(4))) float f32x4;
typedef __attribute__((ext_vector_type(4))) unsigned int u32x4;
using u16 = unsigned short;
typedef unsigned int u32;

__device__ __forceinline__ u16 f2bf(float f) {
    u32 u = __builtin_bit_cast(u32, f);
    u32 r = u + 0x7FFFu + ((u >> 16) & 1u);
    return (u16)(r >> 16);
}

__device__ __forceinline__ float bf2f(u32 w) {  // low 16 bits = bf16
    return __builtin_bit_cast(float, w << 16);
}
__device__ __forceinline__ float bf2f_hi(u32 w) {
    return __builtin_bit_cast(float, w & 0xFFFF0000u);
}

__device__ __forceinline__ float exp2fast(float x) {
    return __builtin_amdgcn_exp2f(x);  // v_exp_f32
}

__device__ __forceinline__ u32 cvtpk(float lo, float hi) {
    u32 r;
    asm("v_cvt_pk_bf16_f32 %0, %1, %2" : "=v"(r) : "v"(lo), "v"(hi));
    return r;
}

__device__ __forceinline__ void async_load16(const void* g, void* l) {
    __builtin_amdgcn_global_load_lds(
        (const __attribute__((address_space(1))) void*)g,
        (__attribute__((address_space(3))) void*)l, 16, 0, 0);
}

__device__ __forceinline__ void wg_barrier() {
    asm volatile("" ::: "memory");
    __builtin_amdgcn_s_barrier();
    asm volatile("" ::: "memory");
}

// ---------------- transpose body: w[K][N] tile -> wt[N][K], 32x32 ----------------
__device__ __forceinline__ void convt_body(const float* __restrict__ w,
                                           u16* __restrict__ wt, int K, int N,
                                           int bn, int bk) {
    __shared__ float tile[32][33];
    int tx = threadIdx.x & 31, ty = threadIdx.x >> 5;
#pragma unroll
    for (int i = 0; i < 4; i++)
        tile[ty + i * 8][tx] = w[(size_t)(bk + ty + i * 8) * N + bn + tx];
    __syncthreads();
#pragma unroll
    for (int i = 0; i < 4; i++)
        wt[(size_t)(bn + ty + i * 8) * K + bk + tx] = f2bf(tile[tx][ty + i * 8]);
}

// ---------------- LayerNorm row body (fp32 in, bf16 out) ----------------
__device__ __forceinline__ void ln_body(const float* __restrict__ x,
                                        const float* __restrict__ ga,
                                        const float* __restrict__ gb,
                                        u16* __restrict__ out, int row) {
    const float4* xr = (const float4*)(x + (size_t)row * 1024);
    float4 v = xr[threadIdx.x];
    float s  = v.x + v.y + v.z + v.w;
    float s2 = v.x * v.x + v.y * v.y + v.z * v.z + v.w * v.w;
#pragma unroll
    for (int off = 32; off; off >>= 1) {
        s  += __shfl_down(s, off);
        s2 += __shfl_down(s2, off);
    }
    __shared__ float rs[4], rs2[4];
    int wid = threadIdx.x >> 6, lane = threadIdx.x & 63;
    if (lane == 0) { rs[wid] = s; rs2[wid] = s2; }
    __syncthreads();
    float S  = rs[0] + rs[1] + rs[2] + rs[3];
    float S2 = rs2[0] + rs2[1] + rs2[2] + rs2[3];
    float mean = S * (1.0f / 1024.0f);
    float var  = fmaxf((S2 - 1024.0f * mean * mean) * (1.0f / 1023.0f), 0.0f);
    float scale = ga[0] / (sqrtf(var) + 1e-6f);
    float shift = gb[0] - mean * scale;
    uint2 pv;
    pv.x = (u32)f2bf(v.x * scale + shift) | ((u32)f2bf(v.y * scale + shift) << 16);
    pv.y = (u32)f2bf(v.z * scale + shift) | ((u32)f2bf(v.w * scale + shift) << 16);
    *(uint2*)(out + (size_t)row * 1024 + threadIdx.x * 4) = pv;
}

// ---------------- fused prep: 6 weight transposes + bias concat + LN1, one launch ----------------
__global__ __launch_bounds__(256) void prep_kernel(const float* __restrict__ wq,
                                                   const float* __restrict__ wk,
                                                   const float* __restrict__ wv,
                                                   const float* __restrict__ wo,
                                                   const float* __restrict__ w1,
                                                   const float* __restrict__ w2,
                                                   u16* __restrict__ wqkvt,
                                                   u16* __restrict__ wot,
                                                   u16* __restrict__ w1t,
                                                   u16* __restrict__ w2t,
                                                   const float* __restrict__ bq,
                                                   const float* __restrict__ bk,
                                                   const float* __restrict__ bv,
                                                   float* __restrict__ bqkv,
                                                   const float* __restrict__ x,
                                                   const float* __restrict__ ln1a,
                                                   const float* __restrict__ ln1b,
                                                   u16* __restrict__ xn1) {
    int bid = blockIdx.x;
    if (bid < 4096) {
        int z = bid >> 10, idx = bid & 1023;
        const float* w = (z == 0) ? wq : (z == 1) ? wk : (z == 2) ? wv : wo;
        u16* wt = (z == 0) ? wqkvt : (z == 1) ? wqkvt + 1024 * 1024
                 : (z == 2) ? wqkvt + 2048 * 1024 : wot;
        convt_body(w, wt, 1024, 1024, (idx & 31) * 32, (idx >> 5) * 32);
    } else if (bid < 8192) {
        int idx = bid - 4096;  // w1: K=1024, N=4096
        convt_body(w1, w1t, 1024, 4096, (idx & 127) * 32, (idx >> 7) * 32);
    } else if (bid < 12288) {
        int idx = bid - 8192;  // w2: K=4096, N=1024
        convt_body(w2, w2t, 4096, 1024, (idx & 31) * 32, (idx >> 5) * 32);
    } else if (bid < 12300) {
        int i = (bid - 12288) * 256 + threadIdx.x;  // 3072 total
        float v = (i < 1024) ? bq[i] : ((i < 2048) ? bk[i - 1024] : bv[i - 2048]);
        bqkv[i] = v;
    } else {
        ln_body(x, ln1a, ln1b, xn1, bid - 12300);  // 4096 rows
    }
}

// ---- fused reduce (3 bf16 partials): dst = dst + p0 + p1 + p2 + bias + resid ----
__global__ __launch_bounds__(256) void addbias3b_kernel(float* __restrict__ dst,
                                                        const u16* __restrict__ p0,
                                                        const u16* __restrict__ p1,
                                                        const u16* __restrict__ p2,
                                                        const float* __restrict__ bias,
                                                        const float* __restrict__ resid) {
    int i4 = blockIdx.x * 256 + threadIdx.x;
    float4 d  = ((const float4*)dst)[i4];
    uint2 ua = ((const uint2*)p0)[i4];
    uint2 ub = ((const uint2*)p1)[i4];
    uint2 uc = ((const uint2*)p2)[i4];
    float4 rr = ((const float4*)resid)[i4];
    float4 bb = *(const float4*)(bias + ((i4 * 4) & 1023));
    d.x += bf2f(ua.x) + bf2f(ub.x) + bf2f(uc.x) + bb.x + rr.x;
    d.y += bf2f_hi(ua.x) + bf2f_hi(ub.x) + bf2f_hi(uc.x) + bb.y + rr.y;
    d.z += bf2f(ua.y) + bf2f(ub.y) + bf2f(uc.y) + bb.z + rr.z;
    d.w += bf2f_hi(ua.y) + bf2f_hi(ub.y) + bf2f_hi(uc.y) + bb.w + rr.w;
    ((float4*)dst)[i4] = d;
}

// ---- fused reduce (3 bf16 partials) + bias + resid + LayerNorm: x1, xn = LN(x1) bf16 ----
__global__ __launch_bounds__(256) void addbias3b_ln_kernel(float* __restrict__ dst,
                                                           const u16* __restrict__ p0,
                                                           const u16* __restrict__ p1,
                                                           const u16* __restrict__ p2,
                                                           const float* __restrict__ bias,
                                                           const float* __restrict__ resid,
                                                           const float* __restrict__ ga,
                                                           const float* __restrict__ gb,
                                                           u16* __restrict__ xn) {
    int row = blockIdx.x;
    int i4 = row * 256 + threadIdx.x;
    float4 d  = ((const float4*)dst)[i4];
    uint2 ua = ((const uint2*)p0)[i4];
    uint2 ub = ((const uint2*)p1)[i4];
    uint2 uc = ((const uint2*)p2)[i4];
    float4 rr = ((const float4*)resid)[i4];
    float4 bb = *(const float4*)(bias + threadIdx.x * 4);
    d.x += bf2f(ua.x) + bf2f(ub.x) + bf2f(uc.x) + bb.x + rr.x;
    d.y += bf2f_hi(ua.x) + bf2f_hi(ub.x) + bf2f_hi(uc.x) + bb.y + rr.y;
    d.z += bf2f(ua.y) + bf2f(ub.y) + bf2f(uc.y) + bb.z + rr.z;
    d.w += bf2f_hi(ua.y) + bf2f_hi(ub.y) + bf2f_hi(uc.y) + bb.w + rr.w;
    ((float4*)dst)[i4] = d;

    float s  = d.x + d.y + d.z + d.w;
    float s2 = d.x * d.x + d.y * d.y + d.z * d.z + d.w * d.w;
#pragma unroll
    for (int off = 32; off; off >>= 1) {
        s  += __shfl_down(s, off);
        s2 += __shfl_down(s2, off);
    }
    __shared__ float rs[4], rs2[4];
    int wid = threadIdx.x >> 6, lane = threadIdx.x & 63;
    if (lane == 0) { rs[wid] = s; rs2[wid] = s2; }
    __syncthreads();
    float S  = rs[0] + rs[1] + rs[2] + rs[3];
    float S2 = rs2[0] + rs2[1] + rs2[2] + rs2[3];
    float mean = S * (1.0f / 1024.0f);
    float var  = fmaxf((S2 - 1024.0f * mean * mean) * (1.0f / 1023.0f), 0.0f);
    float scale = ga[0] / (sqrtf(var) + 1e-6f);
    float shift = gb[0] - mean * scale;
    uint2 pv;
    pv.x = (u32)f2bf(d.x * scale + shift) | ((u32)f2bf(d.y * scale + shift) << 16);
    pv.y = (u32)f2bf(d.z * scale + shift) | ((u32)f2bf(d.w * scale + shift) << 16);
    *(uint2*)(xn + (size_t)row * 1024 + threadIdx.x * 4) = pv;
}

// ---------------- 256x256 8-wave GEMM, BK=64, 4-phase, swizzled LDS, counted vmcnt ----------------
// MODE 0: bf16 out + bias (+relu). VQKV: cols>=2048 (V) are written TRANSPOSED to P0 (=vT).
// MODE 2: split-K via blockIdx.y; z<last -> bf16 partial to P[z]; z==last -> f32 to Cf.
template <int MODE, int RELU, int VQKV>
__global__ __launch_bounds__(512) void gemm256_bt(const u16* __restrict__ A,
                                                  const u16* __restrict__ Bt,
                                                  const float* __restrict__ bias,
                                                  u16* __restrict__ C,
                                                  u16* __restrict__ P0,
                                                  u16* __restrict__ P1,
                                                  u16* __restrict__ P2,
                                                  float* __restrict__ Cf,
                                                  int M, int N, int K, int tilesN, int kLen) {
    __shared__ u16 lds[2][2][16384];
    const int tid = threadIdx.x;
    const int lane = tid & 63, wid = tid >> 6;
    const int l15 = lane & 15, l4 = lane >> 4;
    const int wm = wid >> 2, wn = wid & 3;

    int nwg = gridDim.x;
    int bid = blockIdx.x;
    int swz = (bid & 7) * (nwg >> 3) + (bid >> 3);
    int ty = swz / tilesN, tx = swz % tilesN;
    const int kOff = blockIdx.y * kLen;

    const u16* Ag = A + (size_t)(ty * 256) * K;
    const u16* Bg = Bt + (size_t)(tx * 256) * K;

    auto stage_half = [&](int slot, int ab, int half, const u16* G, int k0) {
#pragma unroll
        for (int j = 0; j < 2; j++) {
            int off16 = half * 1024 + j * 512 + tid;
            int r = off16 >> 3;
            int gs = (off16 & 7) ^ (r & 7);
            const u16* src = G + (size_t)r * K + k0 + gs * 8;
            u16* dst = &lds[slot][ab][(size_t)(half * 1024 + j * 512 + (wid << 6)) * 8];
            async_load16(src, dst);
        }
    };

    f32x4 acc[8][4] = {};
    const int nT = kLen >> 6;

    stage_half(0, 0, 0, Ag, kOff);
    stage_half(0, 0, 1, Ag, kOff);
    stage_half(0, 1, 0, Bg, kOff);
    stage_half(0, 1, 1, Bg, kOff);
    __builtin_amdgcn_sched_barrier(0);

    for (int t = 0; t < nT; ++t) {
        const int cs = t & 1, ns = cs ^ 1;
        const int k1 = kOff + ((t + 1) << 6);
        const bool pf = (t + 1 < nT);
#pragma unroll
        for (int ph = 0; ph < 4; ++ph) {
            if (ph == 0 && pf) { stage_half(ns, 0, 0, Ag, k1); stage_half(ns, 0, 1, Ag, k1); }
            if (ph == 1 && pf) { stage_half(ns, 1, 0, Bg, k1); stage_half(ns, 1, 1, Bg, k1); }
            __builtin_amdgcn_sched_barrier(0);
            if (ph == 0) {
                if (pf) asm volatile("s_waitcnt vmcnt(4)" ::: "memory");
                else    asm volatile("s_waitcnt vmcnt(0)" ::: "memory");
            }
            wg_barrier();

            const int rh = ph >> 1, ch = ph & 1;
            const u16* la = &lds[cs][0][0];
            const u16* lb = &lds[cs][1][0];
            short8 af[4][2], bf[2][2];
#pragma unroll
            for (int m2 = 0; m2 < 4; m2++) {
                int ra = wm * 128 + rh * 64 + m2 * 16 + l15;
#pragma unroll
                for (int ks = 0; ks < 2; ks++) {
                    int sl = (l4 + ks * 4) ^ (ra & 7);
                    af[m2][ks] = *(const short8*)&la[ra * 64 + sl * 8];
                }
            }
#pragma unroll
            for (int n2 = 0; n2 < 2; n2++) {
                int rb = wn * 64 + ch * 32 + n2 * 16 + l15;
#pragma unroll
                for (int ks = 0; ks < 2; ks++) {
                    int sl = (l4 + ks * 4) ^ (rb & 7);
                    bf[n2][ks] = *(const short8*)&lb[rb * 64 + sl * 8];
                }
            }
            __builtin_amdgcn_s_setprio(1);
#pragma unroll
            for (int m2 = 0; m2 < 4; m2++)
#pragma unroll
                for (int n2 = 0; n2 < 2; n2++)
#pragma unroll
                    for (int ks = 0; ks < 2; ks++)
                        acc[rh * 4 + m2][ch * 2 + n2] = __builtin_amdgcn_mfma_f32_16x16x32_bf16(
                            af[m2][ks], bf[n2][ks], acc[rh * 4 + m2][ch * 2 + n2], 0, 0, 0);
            __builtin_amdgcn_s_setprio(0);
            wg_barrier();
        }
    }

    if (MODE == 0) {
#pragma unroll
        for (int mi = 0; mi < 8; mi++) {
            int row0 = ty * 256 + wm * 128 + (mi >> 2) * 64 + (mi & 3) * 16 + l4 * 4;
#pragma unroll
            for (int ni = 0; ni < 4; ni++) {
                int col = tx * 256 + wn * 64 + (ni >> 1) * 32 + (ni & 1) * 16 + l15;
                float bc = bias[col];
                float v0 = acc[mi][ni][0] + bc;
                float v1 = acc[mi][ni][1] + bc;
                float v2 = acc[mi][ni][2] + bc;
                float v3 = acc[mi][ni][3] + bc;
                if (RELU) {
                    v0 = fmaxf(v0, 0.0f); v1 = fmaxf(v1, 0.0f);
                    v2 = fmaxf(v2, 0.0f); v3 = fmaxf(v3, 0.0f);
                }
                if (VQKV && col >= 2048) {
                    // V-part: write transposed directly to vT[b*1024 + (col-2048)][s]
                    uint2 wv;
                    wv.x = cvtpk(v0, v1);
                    wv.y = cvtpk(v2, v3);
                    int bb2 = row0 >> 11, s0 = row0 & 2047;
                    *(uint2*)(P0 + (size_t)(bb2 * 1024 + col - 2048) * 2048 + s0) = wv;
                } else {
                    C[(size_t)(row0 + 0) * N + col] = f2bf(v0);
                    C[(size_t)(row0 + 1) * N + col] = f2bf(v1);
                    C[(size_t)(row0 + 2) * N + col] = f2bf(v2);
                    C[(size_t)(row0 + 3) * N + col] = f2bf(v3);
                }
            }
        }
    } else {
        int z = blockIdx.y;
        bool last = (z == gridDim.y - 1);
        u16* P = (z == 0) ? P0 : (z == 1) ? P1 : P2;
#pragma unroll
        for (int mi = 0; mi < 8; mi++) {
            int row0 = ty * 256 + wm * 128 + (mi >> 2) * 64 + (mi & 3) * 16 + l4 * 4;
#pragma unroll
            for (int ni = 0; ni < 4; ni++) {
                int col = tx * 256 + wn * 64 + (ni >> 1) * 32 + (ni & 1) * 16 + l15;
#pragma unroll
                for (int jj = 0; jj < 4; jj++) {
                    float v = acc[mi][ni][jj];
                    if (last) Cf[(size_t)(row0 + jj) * N + col] = v;
                    else      P[(size_t)(row0 + jj) * N + col] = f2bf(v);
                }
            }
        }
    }
}

// ---------------- flash attention v6 (measured best): 8-wave split-S, PT-LDS P relayout ----------------
__global__ __launch_bounds__(512) void attn_kernel(const u16* __restrict__ qkv,
                                                   const u16* __restrict__ vT,
                                                   const int* __restrict__ mask,
                                                   u16* __restrict__ ctx) {
    const int S = 2048;
    const float C = 0.180336880f;  // 0.125 * log2(e)
    int qt = blockIdx.x;
    int bh = blockIdx.y;
    int b = bh >> 4, h = bh & 15;
    int tid = threadIdx.x;
    int wid = tid >> 6, lane = tid & 63;
    int l15 = lane & 15, l4 = lane >> 4;
    int g = wid >> 2, qw = wid & 3;

    __shared__ u16 Ks[2][64][72];
    __shared__ u16 Vs[2][64][72];
    __shared__ u32 PT[8][16][38];
    __shared__ float mbuf[2][4][16], lbuf[2][4][16];
    __shared__ int mflag;

    if (tid == 0) mflag = 1;
    __syncthreads();
    {
        const int* mrow = mask + b * S;
        int ok = 1;
#pragma unroll
        for (int i = 0; i < 4; i++) ok &= (mrow[tid * 4 + i] != 0);
        if (!ok) mflag = 0;
    }

    int qrow0 = qt * 64 + qw * 16;
    const u16* qb = qkv + (size_t)(b * S + qrow0) * 3072 + h * 64;
    short8 qf0 = *(const short8*)(qb + (size_t)l15 * 3072 + l4 * 8);
    short8 qf1 = *(const short8*)(qb + (size_t)l15 * 3072 + 32 + l4 * 8);

    f32x4 o[4] = {};
    float m_i = -1e30f, lp = 0.0f;
    __syncthreads();
    const int allones = mflag;
    const int* mrow = mask + b * S;

    int tl = tid & 255;
    int srow = tl >> 3, c8 = (tl & 7) * 8;
    const int kt0 = g * 16;
    short8 kreg[2], vreg[2];
#pragma unroll
    for (int p = 0; p < 2; p++) {
        int r = p * 32 + srow;
        kreg[p] = *(const short8*)(qkv + (size_t)(b * S + kt0 * 64 + r) * 3072 + 1024 + h * 64 + c8);
        vreg[p] = *(const short8*)(vT + (size_t)(bh * 64 + r) * 2048 + kt0 * 64 + c8);
    }

    for (int it = 0; it < 16; ++it) {
        const int kt = kt0 + it;
        wg_barrier();
#pragma unroll
        for (int p = 0; p < 2; p++) {
            int r = p * 32 + srow;
            *(short8*)&Ks[g][r][c8] = kreg[p];
            *(short8*)&Vs[g][r][c8] = vreg[p];
        }
        if (it + 1 < 16) {
#pragma unroll
            for (int p = 0; p < 2; p++) {
                int r = p * 32 + srow;
                kreg[p] = *(const short8*)(qkv + (size_t)(b * S + (kt + 1) * 64 + r) * 3072 + 1024 + h * 64 + c8);
                vreg[p] = *(const short8*)(vT + (size_t)(bh * 64 + r) * 2048 + (kt + 1) * 64 + c8);
            }
        }
        asm volatile("s_waitcnt lgkmcnt(0)" ::: "memory");
        wg_barrier();

        float sc[4][4];
#pragma unroll
        for (int kc = 0; kc < 4; kc++) {
            short8 kf0 = *(const short8*)&Ks[g][kc * 16 + l15][l4 * 8];
            short8 kf1 = *(const short8*)&Ks[g][kc * 16 + l15][32 + l4 * 8];
            f32x4 a = {};
            a = __builtin_amdgcn_mfma_f32_16x16x32_bf16(kf0, qf0, a, 0, 0, 0);
            a = __builtin_amdgcn_mfma_f32_16x16x32_bf16(kf1, qf1, a, 0, 0, 0);
            if (allones) {
#pragma unroll
                for (int j = 0; j < 4; j++) sc[kc][j] = a[j];
            } else {
#pragma unroll
                for (int j = 0; j < 4; j++) {
                    int mk = mrow[kt * 64 + kc * 16 + l4 * 4 + j];
                    sc[kc][j] = mk ? a[j] : -1e9f;
                }
            }
        }

        float lm = sc[0][0];
#pragma unroll
        for (int kc = 0; kc < 4; kc++)
#pragma unroll
            for (int j = 0; j < 4; j++) lm = fmaxf(lm, sc[kc][j]);
        if (!__all(lm <= m_i + 64.0f)) {
            float t = lm;
            t = fmaxf(t, __shfl_xor(t, 16));
            t = fmaxf(t, __shfl_xor(t, 32));
            float newm = fmaxf(m_i, t);
            float r = exp2fast((m_i - newm) * C);
            lp *= r;
            float rr0 = __shfl(r, l4 * 4 + 0);
            float rr1 = __shfl(r, l4 * 4 + 1);
            float rr2 = __shfl(r, l4 * 4 + 2);
            float rr3 = __shfl(r, l4 * 4 + 3);
#pragma unroll
            for (int dc = 0; dc < 4; dc++) {
                o[dc][0] *= rr0; o[dc][1] *= rr1; o[dc][2] *= rr2; o[dc][3] *= rr3;
            }
            m_i = newm;
        }

        float nb = -m_i * C;
#pragma unroll
        for (int kc = 0; kc < 4; kc++) {
            float p0 = exp2fast(fmaf(sc[kc][0], C, nb));
            float p1 = exp2fast(fmaf(sc[kc][1], C, nb));
            float p2 = exp2fast(fmaf(sc[kc][2], C, nb));
            float p3 = exp2fast(fmaf(sc[kc][3], C, nb));
            lp += (p0 + p1) + (p2 + p3);
            uint2 w;
            w.x = cvtpk(p0, p1);
            w.y = cvtpk(p2, p3);
            *(uint2*)&PT[wid][l15][kc * 8 + l4 * 2] = w;
        }

        uint2 r01 = *(const uint2*)&PT[wid][l15][l4 * 4];
        uint2 r23 = *(const uint2*)&PT[wid][l15][l4 * 4 + 2];
        uint2 r45 = *(const uint2*)&PT[wid][l15][16 + l4 * 4];
        uint2 r67 = *(const uint2*)&PT[wid][l15][16 + l4 * 4 + 2];
        u32x4 w0 = {r01.x, r01.y, r23.x, r23.y};
        u32x4 w1 = {r45.x, r45.y, r67.x, r67.y};
        short8 pa0 = __builtin_bit_cast(short8, w0);
        short8 pa1 = __builtin_bit_cast(short8, w1);

#pragma unroll
        for (int dc = 0; dc < 4; dc++) {
            short8 vf0 = *(const short8*)&Vs[g][dc * 16 + l15][l4 * 8];
            short8 vf1 = *(const short8*)&Vs[g][dc * 16 + l15][32 + l4 * 8];
            o[dc] = __builtin_amdgcn_mfma_f32_16x16x32_bf16(pa0, vf0, o[dc], 0, 0, 0);
            o[dc] = __builtin_amdgcn_mfma_f32_16x16x32_bf16(pa1, vf1, o[dc], 0, 0, 0);
        }
    }

    // -------- combine the two groups --------
    float lt = lp;
    lt += __shfl_xor(lt, 16);
    lt += __shfl_xor(lt, 32);
    if (l4 == 0) { mbuf[g][qw][l15] = m_i; lbuf[g][qw][l15] = lt; }
    __syncthreads();
    float mo = mbuf[g ^ 1][qw][l15], lo = lbuf[g ^ 1][qw][l15];
    float M  = fmaxf(m_i, mo);
    float rs = exp2fast((m_i - M) * C);
    float ro = exp2fast((mo - M) * C);
    float inv = 1.0f / (rs * lt + ro * lo);
    float rs_j[4], iv_j[4];
#pragma unroll
    for (int j = 0; j < 4; j++) {
        rs_j[j] = __shfl(rs,  l4 * 4 + j);
        iv_j[j] = __shfl(inv, l4 * 4 + j);
    }

    float* obuf = (float*)&Ks[0][0][0];  // 16 KB overlay on dead Ks
#pragma unroll
    for (int c = 0; c < 2; c++) {
        int dce = (g ^ 1) * 2 + c;
#pragma unroll
        for (int j = 0; j < 4; j++)
            obuf[(((g * 4 + qw) * 16) + l4 * 4 + j) * 32 + c * 16 + l15] = o[dce][j] * rs_j[j];
    }
    __syncthreads();
#pragma unroll
    for (int c = 0; c < 2; c++) {
        int dco = g * 2 + c;
#pragma unroll
        for (int j = 0; j < 4; j++) {
            float peer = obuf[((((g ^ 1) * 4 + qw) * 16) + l4 * 4 + j) * 32 + c * 16 + l15];
            float val = (o[dco][j] * rs_j[j] + peer) * iv_j[j];
            int row = qrow0 + l4 * 4 + j;
            ctx[(size_t)(b * S + row) * 1024 + h * 64 + dco * 16 + l15] = f2bf(val);
        }
    }
}

// ---------------- launcher ----------------
extern "C" void kernel_launch(void* const* d_in, const int* in_sizes, int n_in,
                              void* d_out, int out_size, void* d_ws, size_t ws_size,
                              hipStream_t stream) {
    const float* x    = (const float*)d_in[0];
    const int*   mask = (const int*)d_in[1];
    const float* wq   = (const float*)d_in[2];
    const float* bq   = (const float*)d_in[3];
    const float* wk   = (const float*)d_in[4];
    const float* bk   = (const float*)d_in[5];
    const float* wv   = (const float*)d_in[6];
    const float* bv   = (const float*)d_in[7];
    const float* wo   = (const float*)d_in[8];
    const float* bo   = (const float*)d_in[9];
    const float* w1   = (const float*)d_in[10];
    const float* b1   = (const float*)d_in[11];
    const float* w2   = (const float*)d_in[12];
    const float* b2   = (const float*)d_in[13];
    const float* ln1a = (const float*)d_in[14];
    const float* ln1b = (const float*)d_in[15];
    const float* ln2a = (const float*)d_in[16];
    const float* ln2b = (const float*)d_in[17];
    float* out = (float*)d_out;

    char* ws = (char*)d_ws;
    u16*   wqkvt = (u16*)(ws + 0);            //  6 MB (dead after QKV)
    u16*   wot   = (u16*)(ws + 6291456);      //  2 MB (dead after WO)
    u16*   w1t   = (u16*)(ws + 8388608);      //  8 MB (dead after FFN1)
    u16*   w2t   = (u16*)(ws + 16777216);     //  8 MB (live through FFN2)
    float* bqkv  = (float*)(ws + 25165824);   // 12 KB
    char*  regA  = ws + 26214400;
    u16*   xn1   = (u16*)(regA + 0);          //  8 MB (dead after QKV)
    u16*   qkv   = (u16*)(regA + 8388608);    // 24 MB (Q,K used; V region unwritten)
    u16*   ctx   = (u16*)(regA + 33554432);   //  8 MB (dead after WO)
    // vT lives in the x1 region: written by QKV gemm, read by attn, then x1 overwrites (WO gemm)
    u16*   vT    = (u16*)(ws + 68157440);     //  8 MB
    // WO bf16 partials (over dead qkv region):
    u16*   pw0   = (u16*)(regA + 8388608);    //  8 MB
    u16*   pw1   = (u16*)(regA + 16777216);   //  8 MB
    u16*   pw2   = (u16*)(regA + 25165824);   //  8 MB
    float* x1    = (float*)(ws + 68157440);   // 16 MB (aliases vT; written after attn)
    u16*   xn2   = (u16*)(regA + 0);          //  8 MB
    u16*   ff1   = (u16*)(regA + 8388608);    // 32 MB (pw* + ctx dead by FFN1 time)
    // FFN2 bf16 partials (dead regions by FFN2 time):
    u16*   pb0   = (u16*)(ws + 0);            //  8 MB (over wqkvt+wot)
    u16*   pb1   = (u16*)(ws + 8388608);      //  8 MB (over w1t)
    u16*   pb2   = (u16*)(regA + 0);          //  8 MB (over xn2, dead after FFN1)

    dim3 blk(256);

    // all weight transposes + bias concat + LN1 in ONE launch
    prep_kernel<<<dim3(16396), blk, 0, stream>>>(wq, wk, wv, wo, w1, w2,
                                                 wqkvt, wot, w1t, w2t, bq, bk, bv, bqkv,
                                                 x, ln1a, ln1b, xn1);

    // QKV (256^2 8-wave, V written transposed to vT) -> attn -> WO (split-K=4) + reduce+LN2
    gemm256_bt<0, 0, 1><<<dim3(192, 1), dim3(512), 0, stream>>>(
        xn1, wqkvt, bqkv, qkv, vT, nullptr, nullptr, nullptr, 4096, 3072, 1024, 12, 1024);
    attn_kernel<<<dim3(32, 32), dim3(512), 0, stream>>>(qkv, vT, mask, ctx);
    gemm256_bt<2, 0, 0><<<dim3(64, 4), dim3(512), 0, stream>>>(
        ctx, wot, nullptr, nullptr, pw0, pw1, pw2, x1, 4096, 1024, 1024, 4, 256);
    addbias3b_ln_kernel<<<dim3(4096), blk, 0, stream>>>(x1, pw0, pw1, pw2, bo, x, ln2a, ln2b, xn2);

    // FFN1 (256^2 8-wave, relu) -> FFN2 (256^2 8-wave, split-K=4) + reduce(+b2+x1)
    gemm256_bt<0, 1, 0><<<dim3(256, 1), dim3(512), 0, stream>>>(
        xn2, w1t, b1, ff1, nullptr, nullptr, nullptr, nullptr, 4096, 4096, 1024, 16, 1024);
    gemm256_bt<2, 0, 0><<<dim3(64, 4), dim3(512), 0, stream>>>(
        ff1, w2t, nullptr, nullptr, pb0, pb1, pb2, out, 4096, 1024, 4096, 4, 1024);
    addbias3b_kernel<<<dim3(4096), blk, 0, stream>>>(out, pb0, pb1, pb2, b2, x1);
}